// Round 14
// baseline (294.569 us; speedup 1.0000x reference)
//
#include <hip/hip_runtime.h>
#include <stdint.h>

typedef short bf16x8 __attribute__((ext_vector_type(8)));
typedef short s16x4 __attribute__((ext_vector_type(4)));
typedef unsigned short us8 __attribute__((ext_vector_type(8)));
typedef float f32x4 __attribute__((ext_vector_type(4)));
typedef unsigned short u16;
typedef unsigned int u32;

__device__ __forceinline__ u16 f2bf(float f) {
    u32 u = __float_as_uint(f);
    return (u16)((u + 0x7FFFu + ((u >> 16) & 1u)) >> 16);   // RNE
}
__device__ __forceinline__ float bf2f(u16 h) { return __uint_as_float(((u32)h) << 16); }

__device__ __forceinline__ u32 cvtpk(float lo, float hi) {   // D.lo=bf16(lo), D.hi=bf16(hi)
    u32 r;
    asm("v_cvt_pk_bf16_f32 %0, %1, %2" : "=v"(r) : "v"(lo), "v"(hi));
    return r;
}

typedef __attribute__((address_space(3))) unsigned int lds_uint;
typedef const __attribute__((address_space(1))) unsigned int glb_uint;
__device__ __forceinline__ void gld16(const void* g, void* l) {
    __builtin_amdgcn_global_load_lds((glb_uint*)g, (lds_uint*)l, 16, 0, 0);
}

#define VWAIT(n) asm volatile("s_waitcnt vmcnt(" #n ") lgkmcnt(0)" ::: "memory")
#define LWAIT    asm volatile("s_waitcnt lgkmcnt(0)" ::: "memory")
#define BARRIER  do { __builtin_amdgcn_s_barrier(); __builtin_amdgcn_sched_barrier(0); } while (0)

// ---- swizzled staging (rule #21: linear LDS dest + pre-swizzled per-lane global
//      source + matching XOR on the ds_read side) ----

// [128 rows][32 cols] bf16 tile (4-wave); slot = g ^ ((row>>1)&3)
__device__ __forceinline__ void gld_p128x32(const u16* __restrict__ g, int64_t stride,
                                            u16* lds, int w, int lane) {
#pragma unroll
    for (int i = 0; i < 2; ++i) {
        const int grp = w * 2 + i;
        const int row = grp * 16 + (lane >> 2);
        const int sl = (lane & 3) ^ ((row >> 1) & 3);
        gld16(g + (int64_t)row * stride + (sl << 3), &lds[grp * 512]);
    }
}
__device__ __forceinline__ int idx128x32(int row, int gk) {
    return row * 32 + ((gk ^ ((row >> 1) & 3)) << 3);
}

// [R rows][128 cols] bf16 tile (4-wave, R=32 or 64); slot = g ^ (row&7)
__device__ __forceinline__ void gld_t32x128(const u16* __restrict__ g, int64_t stride,
                                            u16* lds, int w, int lane) {
#pragma unroll
    for (int i = 0; i < 2; ++i) {
        const int gg = w * 2 + i;
        const int row = gg * 4 + (lane >> 4);
        const int gs = (lane & 15) ^ (row & 7);
        gld16(g + (int64_t)row * stride + (gs << 3), &lds[gg * 512]);
    }
}
__device__ __forceinline__ void gld_t64x128(const u16* __restrict__ g, int64_t stride,
                                            u16* lds, int w, int lane) {
#pragma unroll
    for (int i = 0; i < 4; ++i) {
        const int gg = w * 4 + i;
        const int row = gg * 4 + (lane >> 4);
        const int gs = (lane & 15) ^ (row & 7);
        gld16(g + (int64_t)row * stride + (gs << 3), &lds[gg * 512]);
    }
}
__device__ __forceinline__ int idxT(int row, int gk) {    // [*][128] read
    return row * 128 + ((gk ^ (row & 7)) << 3);
}

// hi-only MFMA step on two swizzled [128][32] planes (4 waves, 64x64 per wave)
__device__ __forceinline__ void mfma_step1(const u16* LA, const u16* LB,
                                           int wrow, int wcol, int lane,
                                           f32x4 acc[4][4]) {
    const int rl = lane & 15, gk = lane >> 4;
    bf16x8 a[4], bv[4];
#pragma unroll
    for (int i = 0; i < 4; ++i) {
        a[i]  = *reinterpret_cast<const bf16x8*>(&LA[idx128x32(wrow + i * 16 + rl, gk)]);
        bv[i] = *reinterpret_cast<const bf16x8*>(&LB[idx128x32(wcol + i * 16 + rl, gk)]);
    }
#pragma unroll
    for (int m = 0; m < 4; ++m)
#pragma unroll
        for (int n = 0; n < 4; ++n)
            acc[m][n] = __builtin_amdgcn_mfma_f32_16x16x32_bf16(a[m], bv[n], acc[m][n], 0, 0, 0);
}

// ---------------- K0: all four f32->bf16 conversions in one launch
__global__ void k0_all(const float* __restrict__ wqkv, const float* __restrict__ x,
                       const float* __restrict__ ctx, const float* __restrict__ wproj,
                       u16* __restrict__ Wh, u16* __restrict__ Xh,
                       u16* __restrict__ Phw) {
    const int gid = blockIdx.x;
    const float* src; u16* dst; int mode; int lg;
    if (gid < 1536)      { src = wqkv;  dst = Wh;  mode = 0; lg = gid; }
    else if (gid < 3584) { src = x;     dst = Xh;  mode = 1; lg = gid - 1536; }
    else if (gid < 5632) { src = ctx;   dst = Xh;  mode = 2; lg = gid - 3584; }
    else                 { src = wproj; dst = Phw; mode = 0; lg = gid - 5632; }
    const int64_t base = ((int64_t)lg * 256 + threadIdx.x) * 8;
    const int row = (int)(base >> 10), col = (int)(base & 1023);
    int orow = row;
    if (mode == 1) orow = row + ((row >> 10) << 10);
    else if (mode == 2) orow = row + (((row >> 10) + 1) << 10);
    const float4* sp = reinterpret_cast<const float4*>(src + base);
    float4 a = sp[0], b = sp[1];
    float v[8] = {a.x, a.y, a.z, a.w, b.x, b.y, b.z, b.w};
    us8 hh;
#pragma unroll
    for (int j = 0; j < 8; ++j) hh[j] = f2bf(v[j]);
    *reinterpret_cast<us8*>(&dst[(int64_t)orow * 1024 + col]) = hh;
}

// ---------------- K1: qkv = xc @ w_qkv^T  (hi-only bf16) -> Qh  [R8 proven form]
__global__ __launch_bounds__(256, 2) void k1_qkv(const u16* __restrict__ Xh,
                                                 const u16* __restrict__ Wh,
                                                 u16* __restrict__ Qh) {
    __shared__ u16 LA[4096], LB[4096];
    const int tid = threadIdx.x, lane = tid & 63, w = tid >> 6;
    const int wrow = (w >> 1) << 6, wcol = (w & 1) << 6;
    const int n0 = blockIdx.x << 7, m0 = blockIdx.y << 7;
    const u16* Ab = Xh + (int64_t)m0 * 1024;
    const u16* Bb = Wh + (int64_t)n0 * 1024;
    f32x4 acc[4][4] = {};
    for (int kb = 0; kb < 32; ++kb) {
        gld_p128x32(Ab + kb * 32, 1024, LA, w, lane);
        gld_p128x32(Bb + kb * 32, 1024, LB, w, lane);
        __syncthreads();
        mfma_step1(LA, LB, wrow, wcol, lane, acc);
        __syncthreads();
    }
    const int r4 = (lane >> 4) << 2, cc = lane & 15;
#pragma unroll
    for (int m = 0; m < 4; ++m)
#pragma unroll
        for (int n = 0; n < 4; ++n)
#pragma unroll
            for (int j = 0; j < 4; ++j)
                Qh[(int64_t)(m0 + wrow + m * 16 + r4 + j) * 3072
                   + (n0 + wcol + n * 16 + cc)] = f2bf(acc[m][n][j]);
}

// ---------------- K0v: pre-transpose V planes: Vt[z][e 128][kpos 1024]
__global__ __launch_bounds__(256, 2) void k0v_vt(const u16* __restrict__ Qh,
                                                 u16* __restrict__ Vt) {
    __shared__ u16 T[128][144];
    const int tid = threadIdx.x;
    const int z = blockIdx.y, b = z >> 4, h = z & 15;
    const int kt = blockIdx.x;                       // 128-kpos tile
    const int c0v = (h < 8) ? (1024 + h * 128) : (2048 + (h - 8) * 128);
    const u16* Vbase = Qh + ((int64_t)b * 2048 + 1) * 3072 + c0v;
    const int row = tid >> 1, e0 = (tid & 1) << 6;
    const u16* src = Vbase + (int64_t)(kt * 128 + row) * 6144 + e0;
#pragma unroll
    for (int i = 0; i < 8; ++i) {
        us8 v = *reinterpret_cast<const us8*>(src + i * 8);
#pragma unroll
        for (int j = 0; j < 8; ++j) T[e0 + i * 8 + j][row] = v[j];
    }
    __syncthreads();
    const int e = tid >> 1, k0 = (tid & 1) << 6;
    u16* dst = Vt + ((int64_t)z << 17) + (int64_t)e * 1024 + kt * 128 + k0;
#pragma unroll
    for (int i = 0; i < 8; ++i)
        *reinterpret_cast<us8*>(dst + i * 8) = *reinterpret_cast<const us8*>(&T[e][k0 + i * 8]);
}

// ---------------- K23 v6: single fused K/V loop + V DIRECT FROM GLOBAL (L2) +
// streaming deferred attn store. LDS 46KB -> 3 blocks/CU (was 2). Barrier
// pairs 48 -> 32. V fragments are 16B-contiguous in Vt and loaded to VGPRs
// right after the top barrier (latency hides under QK^T+exp). attn stores run
// in a wait-free phase after the sum-reduce. Arithmetic identical to v5.
__global__ __launch_bounds__(256, 3) void k23_fused(const u16* __restrict__ Qh,
                                                    const u16* __restrict__ Vt,
                                                    float* __restrict__ attn,
                                                    u16* __restrict__ Obf) {
    __shared__ u16 LQ[4096];                         // 32x128
    __shared__ u16 LK[2][8192];                      // 2 x (64x128 K)
    __shared__ u16 Ph[32 * 72];                      // p~ bf16 [q][k] (+pad)
    __shared__ float pS[4][32];
    __shared__ float rowInv[32];
    const int tid = threadIdx.x, lane = tid & 63, w = tid >> 6;
    const u32 wgid = blockIdx.x;
    const int xcd = wgid & 7, t0 = wgid >> 3;        // T1: same-z -> same XCD
    const int mt = t0 & 31, z = ((t0 >> 5) << 3) + xcd;
    const int b = z >> 4, h = z & 15;
    const int m0 = mt << 5;                          // 32 q-rows per block
    const u16* Qbase = Qh + ((int64_t)b * 2048 + 2 * m0) * 3072 + h * 128;
    const int pk  = (h < 8) ? 0 : 1;
    const int c0k = (h < 8) ? (2048 + h * 128) : ((h - 8) * 128);
    const u16* Kbase = Qh + ((int64_t)b * 2048 + pk) * 3072 + c0k;
    const u16* Vtz = Vt + ((int64_t)z << 17);
    float* attnZ = attn + ((int64_t)z << 20) + (int64_t)m0 * 1024;
    const int rl = lane & 15, gk = lane >> 4;
    const int r4 = gk << 2;
    const int sm = w & 1, sn = w >> 1;               // PV roles: q-half, e-half
    gld_t32x128(Qbase, 6144, LQ, w, lane);
    gld_t64x128(Kbase, 6144, LK[0], w, lane);        // K chunk 0
    // pk0/pk1[2t+T]: q = T*16+rl, k = t*64 + w*16 + {r4..r4+3}
    u32 pk0[32], pk1[32];
    float ssum0 = 0.f, ssum1 = 0.f;
    f32x4 po[4] = {};
#pragma unroll
    for (int t = 0; t < 16; ++t) {
        VWAIT(0);                                    // K(t) + leftover V-frags landed
        BARRIER;
        if (t < 15)                                  // WAR safe: buf readers were t-1
            gld_t64x128(Kbase + (int64_t)(t + 1) * 64 * 6144, 6144, LK[(t + 1) & 1], w, lane);
        // early V-fragment loads (global, L2-resident; 16B contiguous each);
        // their latency hides under QK^T + exp below
        bf16x8 bv0[4], bv1[4];
#pragma unroll
        for (int n = 0; n < 4; ++n) {
            const u16* vp = Vtz + (int64_t)(sn * 64 + n * 16 + rl) * 1024 + t * 64;
            bv0[n] = *reinterpret_cast<const bf16x8*>(vp + gk * 8);
            bv1[n] = *reinterpret_cast<const bf16x8*>(vp + 32 + gk * 8);
        }
        // QK^T (swapped: D[row=k_sub][col=q])
        f32x4 s0 = {}, s1 = {};
#pragma unroll
        for (int ks = 0; ks < 4; ++ks) {
            bf16x8 kf = *reinterpret_cast<const bf16x8*>(&LK[t & 1][idxT(w * 16 + rl, ks * 4 + gk)]);
            bf16x8 q0 = *reinterpret_cast<const bf16x8*>(&LQ[idxT(rl, ks * 4 + gk)]);
            bf16x8 q1 = *reinterpret_cast<const bf16x8*>(&LQ[idxT(16 + rl, ks * 4 + gk)]);
            s0 = __builtin_amdgcn_mfma_f32_16x16x32_bf16(kf, q0, s0, 0, 0, 0);
            s1 = __builtin_amdgcn_mfma_f32_16x16x32_bf16(kf, q1, s1, 0, 0, 0);
        }
        // exp once + running sums + pack + Ph staging
        float p0[4], p1[4];
#pragma unroll
        for (int j = 0; j < 4; ++j) {
            p0[j] = __expf(s0[j] * 0.125f); ssum0 += p0[j];
            p1[j] = __expf(s1[j] * 0.125f); ssum1 += p1[j];
        }
        const u32 a0 = cvtpk(p0[0], p0[1]), a1 = cvtpk(p0[2], p0[3]);
        const u32 b0 = cvtpk(p1[0], p1[1]), b1 = cvtpk(p1[2], p1[3]);
        pk0[2 * t] = a0; pk1[2 * t] = a1;
        pk0[2 * t + 1] = b0; pk1[2 * t + 1] = b1;
        *reinterpret_cast<uint2*>(&Ph[rl * 72 + w * 16 + r4])        = make_uint2(a0, a1);
        *reinterpret_cast<uint2*>(&Ph[(16 + rl) * 72 + w * 16 + r4]) = make_uint2(b0, b1);
        LWAIT; BARRIER;                              // Ph visible
        // PV: A from Ph, B from the pre-loaded global fragments
        bf16x8 pa0 = *reinterpret_cast<const bf16x8*>(&Ph[(sm * 16 + rl) * 72 + gk * 8]);
        bf16x8 pa1 = *reinterpret_cast<const bf16x8*>(&Ph[(sm * 16 + rl) * 72 + 32 + gk * 8]);
#pragma unroll
        for (int n = 0; n < 4; ++n) {
            po[n] = __builtin_amdgcn_mfma_f32_16x16x32_bf16(pa0, bv0[n], po[n], 0, 0, 0);
            po[n] = __builtin_amdgcn_mfma_f32_16x16x32_bf16(pa1, bv1[n], po[n], 0, 0, 0);
        }
    }
    // ---- stats: reduce sums over k (gk groups), cross-wave combine
    ssum0 += __shfl_xor(ssum0, 16); ssum0 += __shfl_xor(ssum0, 32);
    ssum1 += __shfl_xor(ssum1, 16); ssum1 += __shfl_xor(ssum1, 32);
    if (lane < 16) { pS[w][lane] = ssum0; pS[w][16 + lane] = ssum1; }
    LWAIT; BARRIER;
    if (tid < 32)
        rowInv[tid] = 1.0f / (pS[0][tid] + pS[1][tid] + pS[2][tid] + pS[3][tid]);
    LWAIT; BARRIER;
    const float Iq0 = rowInv[rl], Iq1 = rowInv[16 + rl];
    float IqO[4];
#pragma unroll
    for (int j = 0; j < 4; ++j) IqO[j] = rowInv[sm * 16 + r4 + j];
    // ---- streaming attn store phase: no barriers, no waits — pure BW
#pragma unroll
    for (int t = 0; t < 16; ++t) {
        const u32 a0 = pk0[2 * t], a1 = pk1[2 * t];
        const u32 b0 = pk0[2 * t + 1], b1 = pk1[2 * t + 1];
        *reinterpret_cast<float4*>(&attnZ[(int64_t)rl * 1024 + t * 64 + w * 16 + r4])
            = make_float4(__uint_as_float(a0 << 16) * Iq0,
                          __uint_as_float(a0 & 0xFFFF0000u) * Iq0,
                          __uint_as_float(a1 << 16) * Iq0,
                          __uint_as_float(a1 & 0xFFFF0000u) * Iq0);
        *reinterpret_cast<float4*>(&attnZ[(int64_t)(16 + rl) * 1024 + t * 64 + w * 16 + r4])
            = make_float4(__uint_as_float(b0 << 16) * Iq1,
                          __uint_as_float(b0 & 0xFFFF0000u) * Iq1,
                          __uint_as_float(b1 << 16) * Iq1,
                          __uint_as_float(b1 & 0xFFFF0000u) * Iq1);
    }
    // ---- epilogue: O normalize + scatter
    const int poh = h >> 3, cb2 = (h & 7) << 7;
#pragma unroll
    for (int n = 0; n < 4; ++n)
#pragma unroll
        for (int j = 0; j < 4; ++j) {
            const int qrow = m0 + sm * 16 + r4 + j;
            Obf[((int64_t)b * 2048 + 2 * qrow + poh) * 1024
                + cb2 + sn * 64 + n * 16 + rl] = f2bf(po[n][j] * IqO[j]);
        }
}

// ---------------- K4: out = o @ w_proj^T + b_proj  (hi-only bf16)  [R8 proven form]
__global__ __launch_bounds__(256, 2) void k4_out(const u16* __restrict__ Obf,
                                                 const u16* __restrict__ Phw,
                                                 const float* __restrict__ bias,
                                                 float* __restrict__ out) {
    __shared__ u16 LA[4096], LB[4096];
    const int tid = threadIdx.x, lane = tid & 63, w = tid >> 6;
    const int wrow = (w >> 1) << 6, wcol = (w & 1) << 6;
    const int n0 = blockIdx.x << 7, m0 = blockIdx.y << 7;
    const u16* Ab = Obf + (int64_t)m0 * 1024;
    const u16* Bb = Phw + (int64_t)n0 * 1024;
    f32x4 acc[4][4] = {};
    for (int kb = 0; kb < 32; ++kb) {
        gld_p128x32(Ab + kb * 32, 1024, LA, w, lane);
        gld_p128x32(Bb + kb * 32, 1024, LB, w, lane);
        __syncthreads();
        mfma_step1(LA, LB, wrow, wcol, lane, acc);
        __syncthreads();
    }
    const int r4 = (lane >> 4) << 2, cc = lane & 15;
#pragma unroll
    for (int m = 0; m < 4; ++m)
#pragma unroll
        for (int n = 0; n < 4; ++n)
#pragma unroll
            for (int j = 0; j < 4; ++j)
                out[(int64_t)(m0 + wrow + m * 16 + r4 + j) * 1024
                    + (n0 + wcol + n * 16 + cc)]
                    = acc[m][n][j] + bias[n0 + wcol + n * 16 + cc];
}

extern "C" void kernel_launch(void* const* d_in, const int* in_sizes, int n_in,
                              void* d_out, int out_size, void* d_ws, size_t ws_size,
                              hipStream_t stream) {
    const float* x     = (const float*)d_in[0];
    const float* ctx   = (const float*)d_in[1];
    const float* wqkv  = (const float*)d_in[2];
    const float* wproj = (const float*)d_in[3];
    const float* bias  = (const float*)d_in[4];
    float* out  = (float*)d_out;                 // [4,2048,1024]
    float* attn = out + 8388608;                 // [4,16,1024,1024] f32

    // ws (u16), total 92.3 MB
    u16* Qh  = (u16*)d_ws;                       // [8192,3072]
    u16* Vt  = Qh + 25165824;                    // [64,128,1024]
    u16* Wh  = Vt + 8388608;                     // [3072,1024]
    u16* Phw = Wh + 3145728;                     // [1024,1024]
    u16* Obf = Phw + 1048576;                    // [8192,1024]

    // X bf16 plane parked in the attn region (dead once k1 finishes)
    u16* Xh = (u16*)attn;                        // [8192,1024]

    k0_all   <<<dim3(6144),   256, 0, stream>>>(wqkv, x, ctx, wproj, Wh, Xh, Phw);
    k1_qkv   <<<dim3(24, 64), 256, 0, stream>>>(Xh, Wh, Qh);
    k0v_vt   <<<dim3(8, 64),  256, 0, stream>>>(Qh, Vt);
    k23_fused<<<dim3(2048),   256, 0, stream>>>(Qh, Vt, attn, Obf);
    k4_out   <<<dim3(8, 64),  256, 0, stream>>>(Obf, Phw, bias, out);
}

// Round 15
// 248.066 us; speedup vs baseline: 1.1875x; 1.1875x over previous
//
#include <hip/hip_runtime.h>
#include <stdint.h>

typedef short bf16x8 __attribute__((ext_vector_type(8)));
typedef short s16x4 __attribute__((ext_vector_type(4)));
typedef unsigned short us8 __attribute__((ext_vector_type(8)));
typedef float f32x4 __attribute__((ext_vector_type(4)));
typedef unsigned short u16;
typedef unsigned int u32;

__device__ __forceinline__ u16 f2bf(float f) {
    u32 u = __float_as_uint(f);
    return (u16)((u + 0x7FFFu + ((u >> 16) & 1u)) >> 16);   // RNE
}
__device__ __forceinline__ float bf2f(u16 h) { return __uint_as_float(((u32)h) << 16); }

__device__ __forceinline__ u32 cvtpk(float lo, float hi) {   // D.lo=bf16(lo), D.hi=bf16(hi)
    u32 r;
    asm("v_cvt_pk_bf16_f32 %0, %1, %2" : "=v"(r) : "v"(lo), "v"(hi));
    return r;
}

typedef __attribute__((address_space(3))) unsigned int lds_uint;
typedef const __attribute__((address_space(1))) unsigned int glb_uint;
__device__ __forceinline__ void gld16(const void* g, void* l) {
    __builtin_amdgcn_global_load_lds((glb_uint*)g, (lds_uint*)l, 16, 0, 0);
}

#define VWAIT(n) asm volatile("s_waitcnt vmcnt(" #n ") lgkmcnt(0)" ::: "memory")
#define LWAIT    asm volatile("s_waitcnt lgkmcnt(0)" ::: "memory")
#define BARRIER  do { __builtin_amdgcn_s_barrier(); __builtin_amdgcn_sched_barrier(0); } while (0)

// ---- swizzled staging (rule #21: linear LDS dest + pre-swizzled per-lane global
//      source + matching XOR on the ds_read side) ----

// [128 rows][32 cols] bf16 tile (4-wave); slot = g ^ ((row>>1)&3)
__device__ __forceinline__ void gld_p128x32(const u16* __restrict__ g, int64_t stride,
                                            u16* lds, int w, int lane) {
#pragma unroll
    for (int i = 0; i < 2; ++i) {
        const int grp = w * 2 + i;
        const int row = grp * 16 + (lane >> 2);
        const int sl = (lane & 3) ^ ((row >> 1) & 3);
        gld16(g + (int64_t)row * stride + (sl << 3), &lds[grp * 512]);
    }
}
__device__ __forceinline__ int idx128x32(int row, int gk) {
    return row * 32 + ((gk ^ ((row >> 1) & 3)) << 3);
}

// [R rows][128 cols] bf16 tile (4-wave, R=32 or 64); slot = g ^ (row&7)
__device__ __forceinline__ void gld_t32x128(const u16* __restrict__ g, int64_t stride,
                                            u16* lds, int w, int lane) {
#pragma unroll
    for (int i = 0; i < 2; ++i) {
        const int gg = w * 2 + i;
        const int row = gg * 4 + (lane >> 4);
        const int gs = (lane & 15) ^ (row & 7);
        gld16(g + (int64_t)row * stride + (gs << 3), &lds[gg * 512]);
    }
}
__device__ __forceinline__ void gld_t64x128(const u16* __restrict__ g, int64_t stride,
                                            u16* lds, int w, int lane) {
#pragma unroll
    for (int i = 0; i < 4; ++i) {
        const int gg = w * 4 + i;
        const int row = gg * 4 + (lane >> 4);
        const int gs = (lane & 15) ^ (row & 7);
        gld16(g + (int64_t)row * stride + (gs << 3), &lds[gg * 512]);
    }
}
__device__ __forceinline__ int idxT(int row, int gk) {    // [*][128] read
    return row * 128 + ((gk ^ (row & 7)) << 3);
}

// [128 rows][64 cols] bf16 tile (V^T chunk, 4-wave); slot = g3 ^ (row&7)
__device__ __forceinline__ void gld_v128x64(const u16* __restrict__ g, int64_t stride,
                                            u16* lds, int w, int lane) {
#pragma unroll
    for (int i = 0; i < 4; ++i) {
        const int seg = w * 4 + i;
        const int row = seg * 8 + (lane >> 3);
        const int gs = (lane & 7) ^ (row & 7);
        gld16(g + (int64_t)row * stride + (gs << 3), &lds[seg * 512]);
    }
}
__device__ __forceinline__ int idxV(int row, int g3) {    // [128][64] read
    return row * 64 + ((g3 ^ (row & 7)) << 3);
}

// hi-only MFMA step on two swizzled [128][32] planes (4 waves, 64x64 per wave)
__device__ __forceinline__ void mfma_step1(const u16* LA, const u16* LB,
                                           int wrow, int wcol, int lane,
                                           f32x4 acc[4][4]) {
    const int rl = lane & 15, gk = lane >> 4;
    bf16x8 a[4], bv[4];
#pragma unroll
    for (int i = 0; i < 4; ++i) {
        a[i]  = *reinterpret_cast<const bf16x8*>(&LA[idx128x32(wrow + i * 16 + rl, gk)]);
        bv[i] = *reinterpret_cast<const bf16x8*>(&LB[idx128x32(wcol + i * 16 + rl, gk)]);
    }
#pragma unroll
    for (int m = 0; m < 4; ++m)
#pragma unroll
        for (int n = 0; n < 4; ++n)
            acc[m][n] = __builtin_amdgcn_mfma_f32_16x16x32_bf16(a[m], bv[n], acc[m][n], 0, 0, 0);
}

// ---------------- K0: all four f32->bf16 conversions in one launch
__global__ void k0_all(const float* __restrict__ wqkv, const float* __restrict__ x,
                       const float* __restrict__ ctx, const float* __restrict__ wproj,
                       u16* __restrict__ Wh, u16* __restrict__ Xh,
                       u16* __restrict__ Phw) {
    const int gid = blockIdx.x;
    const float* src; u16* dst; int mode; int lg;
    if (gid < 1536)      { src = wqkv;  dst = Wh;  mode = 0; lg = gid; }
    else if (gid < 3584) { src = x;     dst = Xh;  mode = 1; lg = gid - 1536; }
    else if (gid < 5632) { src = ctx;   dst = Xh;  mode = 2; lg = gid - 3584; }
    else                 { src = wproj; dst = Phw; mode = 0; lg = gid - 5632; }
    const int64_t base = ((int64_t)lg * 256 + threadIdx.x) * 8;
    const int row = (int)(base >> 10), col = (int)(base & 1023);
    int orow = row;
    if (mode == 1) orow = row + ((row >> 10) << 10);
    else if (mode == 2) orow = row + (((row >> 10) + 1) << 10);
    const float4* sp = reinterpret_cast<const float4*>(src + base);
    float4 a = sp[0], b = sp[1];
    float v[8] = {a.x, a.y, a.z, a.w, b.x, b.y, b.z, b.w};
    us8 hh;
#pragma unroll
    for (int j = 0; j < 8; ++j) hh[j] = f2bf(v[j]);
    *reinterpret_cast<us8*>(&dst[(int64_t)orow * 1024 + col]) = hh;
}

// ---------------- K1: qkv = xc @ w_qkv^T  (hi-only bf16) -> Qh  [R8 proven form]
__global__ __launch_bounds__(256, 2) void k1_qkv(const u16* __restrict__ Xh,
                                                 const u16* __restrict__ Wh,
                                                 u16* __restrict__ Qh) {
    __shared__ u16 LA[4096], LB[4096];
    const int tid = threadIdx.x, lane = tid & 63, w = tid >> 6;
    const int wrow = (w >> 1) << 6, wcol = (w & 1) << 6;
    const int n0 = blockIdx.x << 7, m0 = blockIdx.y << 7;
    const u16* Ab = Xh + (int64_t)m0 * 1024;
    const u16* Bb = Wh + (int64_t)n0 * 1024;
    f32x4 acc[4][4] = {};
    for (int kb = 0; kb < 32; ++kb) {
        gld_p128x32(Ab + kb * 32, 1024, LA, w, lane);
        gld_p128x32(Bb + kb * 32, 1024, LB, w, lane);
        __syncthreads();
        mfma_step1(LA, LB, wrow, wcol, lane, acc);
        __syncthreads();
    }
    const int r4 = (lane >> 4) << 2, cc = lane & 15;
#pragma unroll
    for (int m = 0; m < 4; ++m)
#pragma unroll
        for (int n = 0; n < 4; ++n)
#pragma unroll
            for (int j = 0; j < 4; ++j)
                Qh[(int64_t)(m0 + wrow + m * 16 + r4 + j) * 3072
                   + (n0 + wcol + n * 16 + cc)] = f2bf(acc[m][n][j]);
}

// ---------------- K0v: pre-transpose V planes: Vt[z][e 128][kpos 1024]
__global__ __launch_bounds__(256, 2) void k0v_vt(const u16* __restrict__ Qh,
                                                 u16* __restrict__ Vt) {
    __shared__ u16 T[128][144];
    const int tid = threadIdx.x;
    const int z = blockIdx.y, b = z >> 4, h = z & 15;
    const int kt = blockIdx.x;                       // 128-kpos tile
    const int c0v = (h < 8) ? (1024 + h * 128) : (2048 + (h - 8) * 128);
    const u16* Vbase = Qh + ((int64_t)b * 2048 + 1) * 3072 + c0v;
    const int row = tid >> 1, e0 = (tid & 1) << 6;
    const u16* src = Vbase + (int64_t)(kt * 128 + row) * 6144 + e0;
#pragma unroll
    for (int i = 0; i < 8; ++i) {
        us8 v = *reinterpret_cast<const us8*>(src + i * 8);
#pragma unroll
        for (int j = 0; j < 8; ++j) T[e0 + i * 8 + j][row] = v[j];
    }
    __syncthreads();
    const int e = tid >> 1, k0 = (tid & 1) << 6;
    u16* dst = Vt + ((int64_t)z << 17) + (int64_t)e * 1024 + kt * 128 + k0;
#pragma unroll
    for (int i = 0; i < 8; ++i)
        *reinterpret_cast<us8*>(dst + i * 8) = *reinterpret_cast<const us8*>(&T[e][k0 + i * 8]);
}

// ---------------- K23 v7: v5 (R13 best) + single-barrier pass 2.
// Ph double-buffered: chunk t writes Ph[(t+1)&1] (next chunk's P) while PV
// reads Ph[t&1] (written last chunk, visible via this chunk's top barrier).
// Removes 16 LWAIT+BARRIER pairs and the exp->PV serialization per chunk.
// vmcnt counts stage(4/chunk) + attn stores(2/chunk): steady VWAIT(8).
__global__ __launch_bounds__(256, 2) void k23_fused(const u16* __restrict__ Qh,
                                                    const u16* __restrict__ Vt,
                                                    float* __restrict__ attn,
                                                    u16* __restrict__ Obf) {
    __shared__ u16 LQ[4096];                         // 32x128
    __shared__ u16 LKV[3][8192];                     // 3 x (64x128 K | 128x64 V^T)
    __shared__ u16 Ph[2][32 * 72];                   // p~ bf16 [q][k], double-buffered
    __shared__ float pS[4][32];
    __shared__ float rowInv[32];
    const int tid = threadIdx.x, lane = tid & 63, w = tid >> 6;
    const u32 wgid = blockIdx.x;
    const int xcd = wgid & 7, t0 = wgid >> 3;        // T1: same-z -> same XCD
    const int mt = t0 & 31, z = ((t0 >> 5) << 3) + xcd;
    const int b = z >> 4, h = z & 15;
    const int m0 = mt << 5;                          // 32 q-rows per block
    const u16* Qbase = Qh + ((int64_t)b * 2048 + 2 * m0) * 3072 + h * 128;
    const int pk  = (h < 8) ? 0 : 1;
    const int c0k = (h < 8) ? (2048 + h * 128) : ((h - 8) * 128);
    const u16* Kbase = Qh + ((int64_t)b * 2048 + pk) * 3072 + c0k;
    const u16* Vtz = Vt + ((int64_t)z << 17);
    float* attnZ = attn + ((int64_t)z << 20) + (int64_t)m0 * 1024;
    const int rl = lane & 15, gk = lane >> 4;
    const int r4 = gk << 2;
    const int sm = w & 1, sn = w >> 1;               // PV roles: q-half, e-half
    gld_t32x128(Qbase, 6144, LQ, w, lane);
    gld_t64x128(Kbase,             6144, LKV[0], w, lane);
    gld_t64x128(Kbase + 64 * 6144, 6144, LKV[1], w, lane);
    // ---- pass 1 (unchanged from R13): swapped mfma(K,Q), EXP-ONCE, pack, sums
    u32 pk0[32], pk1[32];
    float ssum0 = 0.f, ssum1 = 0.f;
#pragma unroll
    for (int t = 0; t < 16; ++t) {
        if (t == 15) { VWAIT(0); } else { VWAIT(4); }   // K(t) landed; K(t+1) in flight
        BARRIER;
        if (t < 14)
            gld_t64x128(Kbase + (int64_t)(t + 2) * 64 * 6144, 6144, LKV[(t + 2) % 3], w, lane);
        f32x4 s0 = {}, s1 = {};
#pragma unroll
        for (int ks = 0; ks < 4; ++ks) {
            bf16x8 kf = *reinterpret_cast<const bf16x8*>(&LKV[t % 3][idxT(w * 16 + rl, ks * 4 + gk)]);
            bf16x8 q0 = *reinterpret_cast<const bf16x8*>(&LQ[idxT(rl, ks * 4 + gk)]);
            bf16x8 q1 = *reinterpret_cast<const bf16x8*>(&LQ[idxT(16 + rl, ks * 4 + gk)]);
            s0 = __builtin_amdgcn_mfma_f32_16x16x32_bf16(kf, q0, s0, 0, 0, 0);
            s1 = __builtin_amdgcn_mfma_f32_16x16x32_bf16(kf, q1, s1, 0, 0, 0);
        }
        float p0[4], p1[4];
#pragma unroll
        for (int j = 0; j < 4; ++j) {
            p0[j] = __expf(s0[j] * 0.125f); ssum0 += p0[j];
            p1[j] = __expf(s1[j] * 0.125f); ssum1 += p1[j];
        }
        pk0[2 * t]     = cvtpk(p0[0], p0[1]);
        pk1[2 * t]     = cvtpk(p0[2], p0[3]);
        pk0[2 * t + 1] = cvtpk(p1[0], p1[1]);
        pk1[2 * t + 1] = cvtpk(p1[2], p1[3]);
    }
    // ---- stats: reduce sums over k (gk groups), cross-wave combine
    ssum0 += __shfl_xor(ssum0, 16); ssum0 += __shfl_xor(ssum0, 32);
    ssum1 += __shfl_xor(ssum1, 16); ssum1 += __shfl_xor(ssum1, 32);
    if (lane < 16) { pS[w][lane] = ssum0; pS[w][16 + lane] = ssum1; }
    LWAIT; BARRIER;                                  // all K readers done; buf0/1 free
    gld_v128x64(Vtz,      1024, LKV[0], w, lane);    // V chunks 0,1 overlap stats
    gld_v128x64(Vtz + 64, 1024, LKV[1], w, lane);
    if (tid < 32)
        rowInv[tid] = 1.0f / (pS[0][tid] + pS[1][tid] + pS[2][tid] + pS[3][tid]);
    LWAIT; BARRIER;
    const float Iq0 = rowInv[rl], Iq1 = rowInv[16 + rl];
    float IqO[4];
#pragma unroll
    for (int j = 0; j < 4; ++j) IqO[j] = rowInv[sm * 16 + r4 + j];
    // ---- pass-2 prologue: Ph[0] <- chunk 0's P
    {
        const u32 a0 = pk0[0], a1 = pk1[0], b0 = pk0[1], b1 = pk1[1];
        *reinterpret_cast<uint2*>(&Ph[0][rl * 72 + w * 16 + r4])        = make_uint2(a0, a1);
        *reinterpret_cast<uint2*>(&Ph[0][(16 + rl) * 72 + w * 16 + r4]) = make_uint2(b0, b1);
    }
    LWAIT; BARRIER;
    // ---- pass 2: ONE barrier per chunk. Per chunk t: prefetch V(t+2); write
    // Ph[(t+1)&1]; attn stores for t; PV from Ph[t&1] + LKV[t%3]; LWAIT (drain
    // own ds ops before next top barrier).
    f32x4 po[4] = {};
#pragma unroll
    for (int t = 0; t < 16; ++t) {
        if (t == 0)       { VWAIT(4); }              // V0 landed; V1(4) in flight
        else if (t == 1)  { VWAIT(6); }              // V1 landed; S(2)4+st(0)2 fly
        else if (t == 15) { VWAIT(4); }              // V15 landed; st(13)2+st(14)2 fly
        else              { VWAIT(8); }              // V(t) landed; S(t+1)4+4 stores fly
        BARRIER;                                     // V(t) + Ph[t&1] visible
        if (t < 14)
            gld_v128x64(Vtz + (t + 2) * 64, 1024, LKV[(t + 2) % 3], w, lane);
        if (t < 15) {                                // stage NEXT chunk's P
            const u32 a0 = pk0[2 * t + 2], a1 = pk1[2 * t + 2];
            const u32 b0 = pk0[2 * t + 3], b1 = pk1[2 * t + 3];
            *reinterpret_cast<uint2*>(&Ph[(t + 1) & 1][rl * 72 + w * 16 + r4])
                = make_uint2(a0, a1);
            *reinterpret_cast<uint2*>(&Ph[(t + 1) & 1][(16 + rl) * 72 + w * 16 + r4])
                = make_uint2(b0, b1);
        }
        {                                            // attn stores for chunk t
            const u32 a0 = pk0[2 * t], a1 = pk1[2 * t];
            const u32 b0 = pk0[2 * t + 1], b1 = pk1[2 * t + 1];
            *reinterpret_cast<float4*>(&attnZ[(int64_t)rl * 1024 + t * 64 + w * 16 + r4])
                = make_float4(__uint_as_float(a0 << 16) * Iq0,
                              __uint_as_float(a0 & 0xFFFF0000u) * Iq0,
                              __uint_as_float(a1 << 16) * Iq0,
                              __uint_as_float(a1 & 0xFFFF0000u) * Iq0);
            *reinterpret_cast<float4*>(&attnZ[(int64_t)(16 + rl) * 1024 + t * 64 + w * 16 + r4])
                = make_float4(__uint_as_float(b0 << 16) * Iq1,
                              __uint_as_float(b0 & 0xFFFF0000u) * Iq1,
                              __uint_as_float(b1 << 16) * Iq1,
                              __uint_as_float(b1 & 0xFFFF0000u) * Iq1);
        }
        // PV: A from Ph[t&1] (written last chunk), B from LKV[t%3]
        bf16x8 pa0 = *reinterpret_cast<const bf16x8*>(&Ph[t & 1][(sm * 16 + rl) * 72 + gk * 8]);
        bf16x8 pa1 = *reinterpret_cast<const bf16x8*>(&Ph[t & 1][(sm * 16 + rl) * 72 + 32 + gk * 8]);
#pragma unroll
        for (int n = 0; n < 4; ++n) {
            bf16x8 bv0 = *reinterpret_cast<const bf16x8*>(&LKV[t % 3][idxV(sn * 64 + n * 16 + rl, gk)]);
            bf16x8 bv1 = *reinterpret_cast<const bf16x8*>(&LKV[t % 3][idxV(sn * 64 + n * 16 + rl, 4 + gk)]);
            po[n] = __builtin_amdgcn_mfma_f32_16x16x32_bf16(pa0, bv0, po[n], 0, 0, 0);
            po[n] = __builtin_amdgcn_mfma_f32_16x16x32_bf16(pa1, bv1, po[n], 0, 0, 0);
        }
        LWAIT;                                       // own ds_writes/reads drained
    }
    const int poh = h >> 3, cb2 = (h & 7) << 7;
#pragma unroll
    for (int n = 0; n < 4; ++n)
#pragma unroll
        for (int j = 0; j < 4; ++j) {
            const int qrow = m0 + sm * 16 + r4 + j;
            Obf[((int64_t)b * 2048 + 2 * qrow + poh) * 1024
                + cb2 + sn * 64 + n * 16 + rl] = f2bf(po[n][j] * IqO[j]);
        }
}

// ---------------- K4: out = o @ w_proj^T + b_proj  (hi-only bf16)  [R8 proven form]
__global__ __launch_bounds__(256, 2) void k4_out(const u16* __restrict__ Obf,
                                                 const u16* __restrict__ Phw,
                                                 const float* __restrict__ bias,
                                                 float* __restrict__ out) {
    __shared__ u16 LA[4096], LB[4096];
    const int tid = threadIdx.x, lane = tid & 63, w = tid >> 6;
    const int wrow = (w >> 1) << 6, wcol = (w & 1) << 6;
    const int n0 = blockIdx.x << 7, m0 = blockIdx.y << 7;
    const u16* Ab = Obf + (int64_t)m0 * 1024;
    const u16* Bb = Phw + (int64_t)n0 * 1024;
    f32x4 acc[4][4] = {};
    for (int kb = 0; kb < 32; ++kb) {
        gld_p128x32(Ab + kb * 32, 1024, LA, w, lane);
        gld_p128x32(Bb + kb * 32, 1024, LB, w, lane);
        __syncthreads();
        mfma_step1(LA, LB, wrow, wcol, lane, acc);
        __syncthreads();
    }
    const int r4 = (lane >> 4) << 2, cc = lane & 15;
#pragma unroll
    for (int m = 0; m < 4; ++m)
#pragma unroll
        for (int n = 0; n < 4; ++n)
#pragma unroll
            for (int j = 0; j < 4; ++j)
                out[(int64_t)(m0 + wrow + m * 16 + r4 + j) * 1024
                    + (n0 + wcol + n * 16 + cc)]
                    = acc[m][n][j] + bias[n0 + wcol + n * 16 + cc];
}

extern "C" void kernel_launch(void* const* d_in, const int* in_sizes, int n_in,
                              void* d_out, int out_size, void* d_ws, size_t ws_size,
                              hipStream_t stream) {
    const float* x     = (const float*)d_in[0];
    const float* ctx   = (const float*)d_in[1];
    const float* wqkv  = (const float*)d_in[2];
    const float* wproj = (const float*)d_in[3];
    const float* bias  = (const float*)d_in[4];
    float* out  = (float*)d_out;                 // [4,2048,1024]
    float* attn = out + 8388608;                 // [4,16,1024,1024] f32

    // ws (u16), total 92.3 MB
    u16* Qh  = (u16*)d_ws;                       // [8192,3072]
    u16* Vt  = Qh + 25165824;                    // [64,128,1024]
    u16* Wh  = Vt + 8388608;                     // [3072,1024]
    u16* Phw = Wh + 3145728;                     // [1024,1024]
    u16* Obf = Phw + 1048576;                    // [8192,1024]

    // X bf16 plane parked in the attn region (dead once k1 finishes)
    u16* Xh = (u16*)attn;                        // [8192,1024]

    k0_all   <<<dim3(6144),   256, 0, stream>>>(wqkv, x, ctx, wproj, Wh, Xh, Phw);
    k1_qkv   <<<dim3(24, 64), 256, 0, stream>>>(Xh, Wh, Qh);
    k0v_vt   <<<dim3(8, 64),  256, 0, stream>>>(Qh, Vt);
    k23_fused<<<dim3(2048),   256, 0, stream>>>(Qh, Vt, attn, Obf);
    k4_out   <<<dim3(8, 64),  256, 0, stream>>>(Obf, Phw, bias, out);
}

// Round 16
// 242.960 us; speedup vs baseline: 1.2124x; 1.0210x over previous
//
#include <hip/hip_runtime.h>
#include <stdint.h>

typedef short bf16x8 __attribute__((ext_vector_type(8)));
typedef short s16x4 __attribute__((ext_vector_type(4)));
typedef unsigned short us8 __attribute__((ext_vector_type(8)));
typedef float f32x4 __attribute__((ext_vector_type(4)));
typedef unsigned short u16;
typedef unsigned int u32;

__device__ __forceinline__ u16 f2bf(float f) {
    u32 u = __float_as_uint(f);
    return (u16)((u + 0x7FFFu + ((u >> 16) & 1u)) >> 16);   // RNE
}
__device__ __forceinline__ float bf2f(u16 h) { return __uint_as_float(((u32)h) << 16); }

__device__ __forceinline__ u32 cvtpk(float lo, float hi) {   // D.lo=bf16(lo), D.hi=bf16(hi)
    u32 r;
    asm("v_cvt_pk_bf16_f32 %0, %1, %2" : "=v"(r) : "v"(lo), "v"(hi));
    return r;
}

typedef __attribute__((address_space(3))) unsigned int lds_uint;
typedef const __attribute__((address_space(1))) unsigned int glb_uint;
__device__ __forceinline__ void gld16(const void* g, void* l) {
    __builtin_amdgcn_global_load_lds((glb_uint*)g, (lds_uint*)l, 16, 0, 0);
}

#define VWAIT(n) asm volatile("s_waitcnt vmcnt(" #n ") lgkmcnt(0)" ::: "memory")
#define LWAIT    asm volatile("s_waitcnt lgkmcnt(0)" ::: "memory")
#define BARRIER  do { __builtin_amdgcn_s_barrier(); __builtin_amdgcn_sched_barrier(0); } while (0)

// ---- swizzled staging (rule #21) ----

// [128 rows][32 cols] bf16 tile (4-wave); slot = g ^ ((row>>1)&3)
__device__ __forceinline__ void gld_p128x32(const u16* __restrict__ g, int64_t stride,
                                            u16* lds, int w, int lane) {
#pragma unroll
    for (int i = 0; i < 2; ++i) {
        const int grp = w * 2 + i;
        const int row = grp * 16 + (lane >> 2);
        const int sl = (lane & 3) ^ ((row >> 1) & 3);
        gld16(g + (int64_t)row * stride + (sl << 3), &lds[grp * 512]);
    }
}
__device__ __forceinline__ int idx128x32(int row, int gk) {
    return row * 32 + ((gk ^ ((row >> 1) & 3)) << 3);
}

// [R rows][128 cols] bf16 tile (4-wave, R=32/64); slot = g ^ (row&7)
__device__ __forceinline__ void gld_t32x128(const u16* __restrict__ g, int64_t stride,
                                            u16* lds, int w, int lane) {
#pragma unroll
    for (int i = 0; i < 2; ++i) {
        const int gg = w * 2 + i;
        const int row = gg * 4 + (lane >> 4);
        const int gs = (lane & 15) ^ (row & 7);
        gld16(g + (int64_t)row * stride + (gs << 3), &lds[gg * 512]);
    }
}
__device__ __forceinline__ void gld_t64x128(const u16* __restrict__ g, int64_t stride,
                                            u16* lds, int w, int lane) {
#pragma unroll
    for (int i = 0; i < 4; ++i) {
        const int gg = w * 4 + i;
        const int row = gg * 4 + (lane >> 4);
        const int gs = (lane & 15) ^ (row & 7);
        gld16(g + (int64_t)row * stride + (gs << 3), &lds[gg * 512]);
    }
}
__device__ __forceinline__ int idxT(int row, int gk) {    // [*][128] read
    return row * 128 + ((gk ^ (row & 7)) << 3);
}

// [128 rows][64 cols] bf16 tile (V^T chunk, 4-wave); slot = g3 ^ (row&7)
__device__ __forceinline__ void gld_v128x64(const u16* __restrict__ g, int64_t stride,
                                            u16* lds, int w, int lane) {
#pragma unroll
    for (int i = 0; i < 4; ++i) {
        const int seg = w * 4 + i;
        const int row = seg * 8 + (lane >> 3);
        const int gs = (lane & 7) ^ (row & 7);
        gld16(g + (int64_t)row * stride + (gs << 3), &lds[seg * 512]);
    }
}
__device__ __forceinline__ int idxV(int row, int g3) {    // [128][64] read
    return row * 64 + ((g3 ^ (row & 7)) << 3);
}

// hi-only MFMA step on two swizzled [128][32] planes (4 waves, 64x64 per wave)
__device__ __forceinline__ void mfma_step1(const u16* LA, const u16* LB,
                                           int wrow, int wcol, int lane,
                                           f32x4 acc[4][4]) {
    const int rl = lane & 15, gk = lane >> 4;
    bf16x8 a[4], bv[4];
#pragma unroll
    for (int i = 0; i < 4; ++i) {
        a[i]  = *reinterpret_cast<const bf16x8*>(&LA[idx128x32(wrow + i * 16 + rl, gk)]);
        bv[i] = *reinterpret_cast<const bf16x8*>(&LB[idx128x32(wcol + i * 16 + rl, gk)]);
    }
#pragma unroll
    for (int m = 0; m < 4; ++m)
#pragma unroll
        for (int n = 0; n < 4; ++n)
            acc[m][n] = __builtin_amdgcn_mfma_f32_16x16x32_bf16(a[m], bv[n], acc[m][n], 0, 0, 0);
}

// ---------------- K0: all four f32->bf16 conversions in one launch
__global__ void k0_all(const float* __restrict__ wqkv, const float* __restrict__ x,
                       const float* __restrict__ ctx, const float* __restrict__ wproj,
                       u16* __restrict__ Wh, u16* __restrict__ Xh,
                       u16* __restrict__ Phw) {
    const int gid = blockIdx.x;
    const float* src; u16* dst; int mode; int lg;
    if (gid < 1536)      { src = wqkv;  dst = Wh;  mode = 0; lg = gid; }
    else if (gid < 3584) { src = x;     dst = Xh;  mode = 1; lg = gid - 1536; }
    else if (gid < 5632) { src = ctx;   dst = Xh;  mode = 2; lg = gid - 3584; }
    else                 { src = wproj; dst = Phw; mode = 0; lg = gid - 5632; }
    const int64_t base = ((int64_t)lg * 256 + threadIdx.x) * 8;
    const int row = (int)(base >> 10), col = (int)(base & 1023);
    int orow = row;
    if (mode == 1) orow = row + ((row >> 10) << 10);
    else if (mode == 2) orow = row + (((row >> 10) + 1) << 10);
    const float4* sp = reinterpret_cast<const float4*>(src + base);
    float4 a = sp[0], b = sp[1];
    float v[8] = {a.x, a.y, a.z, a.w, b.x, b.y, b.z, b.w};
    us8 hh;
#pragma unroll
    for (int j = 0; j < 8; ++j) hh[j] = f2bf(v[j]);
    *reinterpret_cast<us8*>(&dst[(int64_t)orow * 1024 + col]) = hh;
}

// ---------------- K1 (8-phase 256x256 template, faithful port):
// BM=BN=256, BK=64, 512 thr = 8 waves (wm 0..1 x wn 0..3). Per-wave output:
// rows {qm*128 + wm*64 +0..63}, cols {qn*128 + wn*32 +0..31} per quadrant.
// LDS ring: 8 half-tile buffers [X: A0,A1,B0,B1][kt&1] of [128][64] bf16.
// Phase = {stage 1 half; vmcnt(6); barrier; ds-read frags; lgkm(0); 16 MFMA
// (setprio); barrier}. Stage schedule (verified WAR/RAW, all deadlines >=4
// phases => uniform vmcnt(6) = 3 half-tiles in flight):
//   p0:A1(t+1) p1:B1(t+1) p2:A0(t+2) p3:B0(t+2) p4:A1(t+2) p5:B1(t+2)
//   p6:A0(t+3) p7:B0(t+3)      (t = 2i; reads: p0-3 par0=t, p4-7 par1=t+1)
// K-accum order identical to the old k1 => bit-identical output.
__global__ __launch_bounds__(512, 1) void k1_qkv(const u16* __restrict__ Xh,
                                                 const u16* __restrict__ Wh,
                                                 u16* __restrict__ Qh) {
    __shared__ u16 L[4][2][8192];                  // 128 KB
    const int tid = threadIdx.x, lane = tid & 63;
    const int w = tid >> 6, wm = w >> 2, wn = w & 3;
    const int rl = lane & 15, gk = lane >> 4, r4 = gk << 2;
    const int n0 = blockIdx.x << 8, m0 = blockIdx.y << 8;
    const u16* Ab = Xh + (int64_t)m0 * 1024;
    const u16* Bb = Wh + (int64_t)n0 * 1024;
    const int srow0 = tid >> 3, scol = tid & 7;
    f32x4 acc[2][4][2][2] = {};
    bf16x8 afr[4][2];

#define STAGE1(X, KT) do { if ((KT) < 16) {                                      \
    const u16* _b = (((X) < 2) ? (Ab + (int64_t)((X) * 128) * 1024)              \
                               : (Bb + (int64_t)(((X) - 2) * 128) * 1024))       \
                    + (KT) * 64;                                                 \
    u16* _l = &L[(X)][(KT) & 1][0];                                              \
    _Pragma("unroll") for (int _j = 0; _j < 2; ++_j) {                           \
        const int _r = _j * 64 + srow0;                                          \
        const int _g = scol ^ (_r & 7);                                          \
        gld16(_b + (int64_t)_r * 1024 + _g * 8, &_l[_r * 64 + scol * 8]);        \
    } } } while (0)

#define RDF(X, PAR, ROW, KHGK)                                                   \
    (*reinterpret_cast<const bf16x8*>(                                           \
        &L[(X)][(PAR)][(ROW) * 64 + (((KHGK) ^ ((ROW) & 7)) << 3)]))

#define PHASE(QM, QN, PAR, STX, STKT) do {                                       \
    STAGE1(STX, STKT);                                                           \
    VWAIT(6);                                                                    \
    __builtin_amdgcn_s_barrier(); __builtin_amdgcn_sched_barrier(0);             \
    if ((QN) == 0) {                                                             \
        _Pragma("unroll") for (int _mf = 0; _mf < 4; ++_mf) {                    \
            afr[_mf][0] = RDF(QM, PAR, wm * 64 + _mf * 16 + rl, gk);             \
            afr[_mf][1] = RDF(QM, PAR, wm * 64 + _mf * 16 + rl, 4 + gk);         \
        } }                                                                      \
    bf16x8 _b00 = RDF(2 + (QN), PAR, wn * 32 + rl, gk);                          \
    bf16x8 _b01 = RDF(2 + (QN), PAR, wn * 32 + rl, 4 + gk);                      \
    bf16x8 _b10 = RDF(2 + (QN), PAR, wn * 32 + 16 + rl, gk);                     \
    bf16x8 _b11 = RDF(2 + (QN), PAR, wn * 32 + 16 + rl, 4 + gk);                 \
    LWAIT; __builtin_amdgcn_sched_barrier(0);                                    \
    __builtin_amdgcn_s_setprio(1);                                               \
    _Pragma("unroll") for (int _mf = 0; _mf < 4; ++_mf) {                        \
        acc[QM][_mf][QN][0] = __builtin_amdgcn_mfma_f32_16x16x32_bf16(           \
            afr[_mf][0], _b00, acc[QM][_mf][QN][0], 0, 0, 0);                    \
        acc[QM][_mf][QN][0] = __builtin_amdgcn_mfma_f32_16x16x32_bf16(           \
            afr[_mf][1], _b01, acc[QM][_mf][QN][0], 0, 0, 0);                    \
        acc[QM][_mf][QN][1] = __builtin_amdgcn_mfma_f32_16x16x32_bf16(           \
            afr[_mf][0], _b10, acc[QM][_mf][QN][1], 0, 0, 0);                    \
        acc[QM][_mf][QN][1] = __builtin_amdgcn_mfma_f32_16x16x32_bf16(           \
            afr[_mf][1], _b11, acc[QM][_mf][QN][1], 0, 0, 0);                    \
    }                                                                            \
    __builtin_amdgcn_s_setprio(0);                                               \
    __builtin_amdgcn_s_barrier(); __builtin_amdgcn_sched_barrier(0);             \
} while (0)

    // prologue: A0(0),B0(0),A1(0),B1(0),A0(1),B0(1)
    STAGE1(0, 0); STAGE1(2, 0); STAGE1(1, 0); STAGE1(3, 0); STAGE1(0, 1); STAGE1(2, 1);
    for (int i = 0; i < 8; ++i) {
        const int t = 2 * i;
        PHASE(0, 0, 0, 1, t + 1);
        PHASE(0, 1, 0, 3, t + 1);
        PHASE(1, 0, 0, 0, t + 2);
        PHASE(1, 1, 0, 2, t + 2);
        PHASE(0, 0, 1, 1, t + 2);
        PHASE(0, 1, 1, 3, t + 2);
        PHASE(1, 0, 1, 0, t + 3);
        PHASE(1, 1, 1, 2, t + 3);
    }
#undef PHASE
#undef RDF
#undef STAGE1
#pragma unroll
    for (int qm = 0; qm < 2; ++qm)
#pragma unroll
        for (int mf = 0; mf < 4; ++mf)
#pragma unroll
            for (int qn = 0; qn < 2; ++qn)
#pragma unroll
                for (int nf = 0; nf < 2; ++nf)
#pragma unroll
                    for (int j = 0; j < 4; ++j) {
                        const int row = m0 + qm * 128 + wm * 64 + mf * 16 + r4 + j;
                        const int col = n0 + qn * 128 + wn * 32 + nf * 16 + rl;
                        Qh[(int64_t)row * 3072 + col] = f2bf(acc[qm][mf][qn][nf][j]);
                    }
}

// ---------------- K0v: pre-transpose V planes: Vt[z][e 128][kpos 1024]
__global__ __launch_bounds__(256, 2) void k0v_vt(const u16* __restrict__ Qh,
                                                 u16* __restrict__ Vt) {
    __shared__ u16 T[128][144];
    const int tid = threadIdx.x;
    const int z = blockIdx.y, b = z >> 4, h = z & 15;
    const int kt = blockIdx.x;
    const int c0v = (h < 8) ? (1024 + h * 128) : (2048 + (h - 8) * 128);
    const u16* Vbase = Qh + ((int64_t)b * 2048 + 1) * 3072 + c0v;
    const int row = tid >> 1, e0 = (tid & 1) << 6;
    const u16* src = Vbase + (int64_t)(kt * 128 + row) * 6144 + e0;
#pragma unroll
    for (int i = 0; i < 8; ++i) {
        us8 v = *reinterpret_cast<const us8*>(src + i * 8);
#pragma unroll
        for (int j = 0; j < 8; ++j) T[e0 + i * 8 + j][row] = v[j];
    }
    __syncthreads();
    const int e = tid >> 1, k0 = (tid & 1) << 6;
    u16* dst = Vt + ((int64_t)z << 17) + (int64_t)e * 1024 + kt * 128 + k0;
#pragma unroll
    for (int i = 0; i < 8; ++i)
        *reinterpret_cast<us8*>(dst + i * 8) = *reinterpret_cast<const us8*>(&T[e][k0 + i * 8]);
}

// ---------------- K23 v5 (R13 best): exp-once fused attention
__global__ __launch_bounds__(256, 2) void k23_fused(const u16* __restrict__ Qh,
                                                    const u16* __restrict__ Vt,
                                                    float* __restrict__ attn,
                                                    u16* __restrict__ Obf) {
    __shared__ u16 LQ[4096];
    __shared__ u16 LKV[3][8192];
    __shared__ u16 Ph[32 * 72];
    __shared__ float pS[4][32];
    __shared__ float rowInv[32];
    const int tid = threadIdx.x, lane = tid & 63, w = tid >> 6;
    const u32 wgid = blockIdx.x;
    const int xcd = wgid & 7, t0 = wgid >> 3;
    const int mt = t0 & 31, z = ((t0 >> 5) << 3) + xcd;
    const int b = z >> 4, h = z & 15;
    const int m0 = mt << 5;
    const u16* Qbase = Qh + ((int64_t)b * 2048 + 2 * m0) * 3072 + h * 128;
    const int pk  = (h < 8) ? 0 : 1;
    const int c0k = (h < 8) ? (2048 + h * 128) : ((h - 8) * 128);
    const u16* Kbase = Qh + ((int64_t)b * 2048 + pk) * 3072 + c0k;
    const u16* Vtz = Vt + ((int64_t)z << 17);
    float* attnZ = attn + ((int64_t)z << 20) + (int64_t)m0 * 1024;
    const int rl = lane & 15, gk = lane >> 4;
    const int r4 = gk << 2;
    const int sm = w & 1, sn = w >> 1;
    gld_t32x128(Qbase, 6144, LQ, w, lane);
    gld_t64x128(Kbase,             6144, LKV[0], w, lane);
    gld_t64x128(Kbase + 64 * 6144, 6144, LKV[1], w, lane);
    u32 pk0[32], pk1[32];
    float ssum0 = 0.f, ssum1 = 0.f;
#pragma unroll
    for (int t = 0; t < 16; ++t) {
        if (t == 15) { VWAIT(0); } else { VWAIT(4); }
        BARRIER;
        if (t < 14)
            gld_t64x128(Kbase + (int64_t)(t + 2) * 64 * 6144, 6144, LKV[(t + 2) % 3], w, lane);
        f32x4 s0 = {}, s1 = {};
#pragma unroll
        for (int ks = 0; ks < 4; ++ks) {
            bf16x8 kf = *reinterpret_cast<const bf16x8*>(&LKV[t % 3][idxT(w * 16 + rl, ks * 4 + gk)]);
            bf16x8 q0 = *reinterpret_cast<const bf16x8*>(&LQ[idxT(rl, ks * 4 + gk)]);
            bf16x8 q1 = *reinterpret_cast<const bf16x8*>(&LQ[idxT(16 + rl, ks * 4 + gk)]);
            s0 = __builtin_amdgcn_mfma_f32_16x16x32_bf16(kf, q0, s0, 0, 0, 0);
            s1 = __builtin_amdgcn_mfma_f32_16x16x32_bf16(kf, q1, s1, 0, 0, 0);
        }
        float p0[4], p1[4];
#pragma unroll
        for (int j = 0; j < 4; ++j) {
            p0[j] = __expf(s0[j] * 0.125f); ssum0 += p0[j];
            p1[j] = __expf(s1[j] * 0.125f); ssum1 += p1[j];
        }
        pk0[2 * t]     = cvtpk(p0[0], p0[1]);
        pk1[2 * t]     = cvtpk(p0[2], p0[3]);
        pk0[2 * t + 1] = cvtpk(p1[0], p1[1]);
        pk1[2 * t + 1] = cvtpk(p1[2], p1[3]);
    }
    ssum0 += __shfl_xor(ssum0, 16); ssum0 += __shfl_xor(ssum0, 32);
    ssum1 += __shfl_xor(ssum1, 16); ssum1 += __shfl_xor(ssum1, 32);
    if (lane < 16) { pS[w][lane] = ssum0; pS[w][16 + lane] = ssum1; }
    LWAIT; BARRIER;
    gld_v128x64(Vtz,      1024, LKV[0], w, lane);
    gld_v128x64(Vtz + 64, 1024, LKV[1], w, lane);
    if (tid < 32)
        rowInv[tid] = 1.0f / (pS[0][tid] + pS[1][tid] + pS[2][tid] + pS[3][tid]);
    LWAIT; BARRIER;
    const float Iq0 = rowInv[rl], Iq1 = rowInv[16 + rl];
    float IqO[4];
#pragma unroll
    for (int j = 0; j < 4; ++j) IqO[j] = rowInv[sm * 16 + r4 + j];
    f32x4 po[4] = {};
#pragma unroll
    for (int t = 0; t < 16; ++t) {
        if (t == 0)       { VWAIT(4); }
        else if (t == 15) { VWAIT(2); }
        else              { VWAIT(6); }
        BARRIER;
        if (t < 14)
            gld_v128x64(Vtz + (t + 2) * 64, 1024, LKV[(t + 2) % 3], w, lane);
        const u32 a0 = pk0[2 * t], a1 = pk1[2 * t];
        const u32 b0 = pk0[2 * t + 1], b1 = pk1[2 * t + 1];
        *reinterpret_cast<uint2*>(&Ph[rl * 72 + w * 16 + r4])        = make_uint2(a0, a1);
        *reinterpret_cast<uint2*>(&Ph[(16 + rl) * 72 + w * 16 + r4]) = make_uint2(b0, b1);
        *reinterpret_cast<float4*>(&attnZ[(int64_t)rl * 1024 + t * 64 + w * 16 + r4])
            = make_float4(__uint_as_float(a0 << 16) * Iq0,
                          __uint_as_float(a0 & 0xFFFF0000u) * Iq0,
                          __uint_as_float(a1 << 16) * Iq0,
                          __uint_as_float(a1 & 0xFFFF0000u) * Iq0);
        *reinterpret_cast<float4*>(&attnZ[(int64_t)(16 + rl) * 1024 + t * 64 + w * 16 + r4])
            = make_float4(__uint_as_float(b0 << 16) * Iq1,
                          __uint_as_float(b0 & 0xFFFF0000u) * Iq1,
                          __uint_as_float(b1 << 16) * Iq1,
                          __uint_as_float(b1 & 0xFFFF0000u) * Iq1);
        LWAIT; BARRIER;
        bf16x8 pa0 = *reinterpret_cast<const bf16x8*>(&Ph[(sm * 16 + rl) * 72 + gk * 8]);
        bf16x8 pa1 = *reinterpret_cast<const bf16x8*>(&Ph[(sm * 16 + rl) * 72 + 32 + gk * 8]);
#pragma unroll
        for (int n = 0; n < 4; ++n) {
            bf16x8 bv0 = *reinterpret_cast<const bf16x8*>(&LKV[t % 3][idxV(sn * 64 + n * 16 + rl, gk)]);
            bf16x8 bv1 = *reinterpret_cast<const bf16x8*>(&LKV[t % 3][idxV(sn * 64 + n * 16 + rl, 4 + gk)]);
            po[n] = __builtin_amdgcn_mfma_f32_16x16x32_bf16(pa0, bv0, po[n], 0, 0, 0);
            po[n] = __builtin_amdgcn_mfma_f32_16x16x32_bf16(pa1, bv1, po[n], 0, 0, 0);
        }
    }
    const int poh = h >> 3, cb2 = (h & 7) << 7;
#pragma unroll
    for (int n = 0; n < 4; ++n)
#pragma unroll
        for (int j = 0; j < 4; ++j) {
            const int qrow = m0 + sm * 16 + r4 + j;
            Obf[((int64_t)b * 2048 + 2 * qrow + poh) * 1024
                + cb2 + sn * 64 + n * 16 + rl] = f2bf(po[n][j] * IqO[j]);
        }
}

// ---------------- K4: out = o @ w_proj^T + b_proj  (hi-only bf16)  [R8 proven form]
__global__ __launch_bounds__(256, 2) void k4_out(const u16* __restrict__ Obf,
                                                 const u16* __restrict__ Phw,
                                                 const float* __restrict__ bias,
                                                 float* __restrict__ out) {
    __shared__ u16 LA[4096], LB[4096];
    const int tid = threadIdx.x, lane = tid & 63, w = tid >> 6;
    const int wrow = (w >> 1) << 6, wcol = (w & 1) << 6;
    const int n0 = blockIdx.x << 7, m0 = blockIdx.y << 7;
    const u16* Ab = Obf + (int64_t)m0 * 1024;
    const u16* Bb = Phw + (int64_t)n0 * 1024;
    f32x4 acc[4][4] = {};
    for (int kb = 0; kb < 32; ++kb) {
        gld_p128x32(Ab + kb * 32, 1024, LA, w, lane);
        gld_p128x32(Bb + kb * 32, 1024, LB, w, lane);
        __syncthreads();
        mfma_step1(LA, LB, wrow, wcol, lane, acc);
        __syncthreads();
    }
    const int r4 = (lane >> 4) << 2, cc = lane & 15;
#pragma unroll
    for (int m = 0; m < 4; ++m)
#pragma unroll
        for (int n = 0; n < 4; ++n)
#pragma unroll
            for (int j = 0; j < 4; ++j)
                out[(int64_t)(m0 + wrow + m * 16 + r4 + j) * 1024
                    + (n0 + wcol + n * 16 + cc)]
                    = acc[m][n][j] + bias[n0 + wcol + n * 16 + cc];
}

extern "C" void kernel_launch(void* const* d_in, const int* in_sizes, int n_in,
                              void* d_out, int out_size, void* d_ws, size_t ws_size,
                              hipStream_t stream) {
    const float* x     = (const float*)d_in[0];
    const float* ctx   = (const float*)d_in[1];
    const float* wqkv  = (const float*)d_in[2];
    const float* wproj = (const float*)d_in[3];
    const float* bias  = (const float*)d_in[4];
    float* out  = (float*)d_out;                 // [4,2048,1024]
    float* attn = out + 8388608;                 // [4,16,1024,1024] f32

    // ws (u16), total 92.3 MB
    u16* Qh  = (u16*)d_ws;                       // [8192,3072]
    u16* Vt  = Qh + 25165824;                    // [64,128,1024]
    u16* Wh  = Vt + 8388608;                     // [3072,1024]
    u16* Phw = Wh + 3145728;                     // [1024,1024]
    u16* Obf = Phw + 1048576;                    // [8192,1024]

    // X bf16 plane parked in the attn region (dead once k1 finishes)
    u16* Xh = (u16*)attn;                        // [8192,1024]

    k0_all   <<<dim3(6144),   256, 0, stream>>>(wqkv, x, ctx, wproj, Wh, Xh, Phw);
    k1_qkv   <<<dim3(12, 32), 512, 0, stream>>>(Xh, Wh, Qh);
    k0v_vt   <<<dim3(8, 64),  256, 0, stream>>>(Qh, Vt);
    k23_fused<<<dim3(2048),   256, 0, stream>>>(Qh, Vt, attn, Obf);
    k4_out   <<<dim3(8, 64),  256, 0, stream>>>(Obf, Phw, bias, out);
}

// Round 17
// 231.792 us; speedup vs baseline: 1.2708x; 1.0482x over previous
//
#include <hip/hip_runtime.h>
#include <stdint.h>

typedef short bf16x8 __attribute__((ext_vector_type(8)));
typedef short s16x4 __attribute__((ext_vector_type(4)));
typedef unsigned short us8 __attribute__((ext_vector_type(8)));
typedef float f32x4 __attribute__((ext_vector_type(4)));
typedef unsigned short u16;
typedef unsigned int u32;

__device__ __forceinline__ u16 f2bf(float f) {
    u32 u = __float_as_uint(f);
    return (u16)((u + 0x7FFFu + ((u >> 16) & 1u)) >> 16);   // RNE
}
__device__ __forceinline__ float bf2f(u16 h) { return __uint_as_float(((u32)h) << 16); }

__device__ __forceinline__ u32 cvtpk(float lo, float hi) {   // D.lo=bf16(lo), D.hi=bf16(hi)
    u32 r;
    asm("v_cvt_pk_bf16_f32 %0, %1, %2" : "=v"(r) : "v"(lo), "v"(hi));
    return r;
}

typedef __attribute__((address_space(3))) unsigned int lds_uint;
typedef const __attribute__((address_space(1))) unsigned int glb_uint;
__device__ __forceinline__ void gld16(const void* g, void* l) {
    __builtin_amdgcn_global_load_lds((glb_uint*)g, (lds_uint*)l, 16, 0, 0);
}

#define VWAIT(n) asm volatile("s_waitcnt vmcnt(" #n ") lgkmcnt(0)" ::: "memory")
#define LWAIT    asm volatile("s_waitcnt lgkmcnt(0)" ::: "memory")
#define BARRIER  do { __builtin_amdgcn_s_barrier(); __builtin_amdgcn_sched_barrier(0); } while (0)

// ---- swizzled staging (rule #21) ----

// [128 rows][32 cols] bf16 tile (4-wave); slot = g ^ ((row>>1)&3)
__device__ __forceinline__ void gld_p128x32(const u16* __restrict__ g, int64_t stride,
                                            u16* lds, int w, int lane) {
#pragma unroll
    for (int i = 0; i < 2; ++i) {
        const int grp = w * 2 + i;
        const int row = grp * 16 + (lane >> 2);
        const int sl = (lane & 3) ^ ((row >> 1) & 3);
        gld16(g + (int64_t)row * stride + (sl << 3), &lds[grp * 512]);
    }
}
__device__ __forceinline__ int idx128x32(int row, int gk) {
    return row * 32 + ((gk ^ ((row >> 1) & 3)) << 3);
}

// [R rows][128 cols] bf16 tile (4-wave, R=32/64); slot = g ^ (row&7)
__device__ __forceinline__ void gld_t32x128(const u16* __restrict__ g, int64_t stride,
                                            u16* lds, int w, int lane) {
#pragma unroll
    for (int i = 0; i < 2; ++i) {
        const int gg = w * 2 + i;
        const int row = gg * 4 + (lane >> 4);
        const int gs = (lane & 15) ^ (row & 7);
        gld16(g + (int64_t)row * stride + (gs << 3), &lds[gg * 512]);
    }
}
__device__ __forceinline__ void gld_t64x128(const u16* __restrict__ g, int64_t stride,
                                            u16* lds, int w, int lane) {
#pragma unroll
    for (int i = 0; i < 4; ++i) {
        const int gg = w * 4 + i;
        const int row = gg * 4 + (lane >> 4);
        const int gs = (lane & 15) ^ (row & 7);
        gld16(g + (int64_t)row * stride + (gs << 3), &lds[gg * 512]);
    }
}
__device__ __forceinline__ int idxT(int row, int gk) {    // [*][128] read
    return row * 128 + ((gk ^ (row & 7)) << 3);
}

// [128 rows][64 cols] bf16 tile (V^T chunk, 4-wave); slot = g3 ^ (row&7)
__device__ __forceinline__ void gld_v128x64(const u16* __restrict__ g, int64_t stride,
                                            u16* lds, int w, int lane) {
#pragma unroll
    for (int i = 0; i < 4; ++i) {
        const int seg = w * 4 + i;
        const int row = seg * 8 + (lane >> 3);
        const int gs = (lane & 7) ^ (row & 7);
        gld16(g + (int64_t)row * stride + (gs << 3), &lds[seg * 512]);
    }
}
__device__ __forceinline__ int idxV(int row, int g3) {    // [128][64] read
    return row * 64 + ((g3 ^ (row & 7)) << 3);
}

// ---------------- K0: all four f32->bf16 conversions in one launch
__global__ void k0_all(const float* __restrict__ wqkv, const float* __restrict__ x,
                       const float* __restrict__ ctx, const float* __restrict__ wproj,
                       u16* __restrict__ Wh, u16* __restrict__ Xh,
                       u16* __restrict__ Phw) {
    const int gid = blockIdx.x;
    const float* src; u16* dst; int mode; int lg;
    if (gid < 1536)      { src = wqkv;  dst = Wh;  mode = 0; lg = gid; }
    else if (gid < 3584) { src = x;     dst = Xh;  mode = 1; lg = gid - 1536; }
    else if (gid < 5632) { src = ctx;   dst = Xh;  mode = 2; lg = gid - 3584; }
    else                 { src = wproj; dst = Phw; mode = 0; lg = gid - 5632; }
    const int64_t base = ((int64_t)lg * 256 + threadIdx.x) * 8;
    const int row = (int)(base >> 10), col = (int)(base & 1023);
    int orow = row;
    if (mode == 1) orow = row + ((row >> 10) << 10);
    else if (mode == 2) orow = row + (((row >> 10) + 1) << 10);
    const float4* sp = reinterpret_cast<const float4*>(src + base);
    float4 a = sp[0], b = sp[1];
    float v[8] = {a.x, a.y, a.z, a.w, b.x, b.y, b.z, b.w};
    us8 hh;
#pragma unroll
    for (int j = 0; j < 8; ++j) hh[j] = f2bf(v[j]);
    *reinterpret_cast<us8*>(&dst[(int64_t)orow * 1024 + col]) = hh;
}

// ---------------- 8-phase GEMM template, BM=256 x BN=128 x BK=64, 512 thr.
// 8 waves (wm 0..1 x wn 0..3); per-wave: rows qm*128+wm*64+mf*16, cols
// qn*64+wn*16. LDS ring: {A0-half, A1-half, B} x 2 parity x 16KB = 96KB.
// Stage schedule per iter (t=2i): p0:A1(t+1) p1:B(t+1) p2:A0(t+2)
// p4:A1(t+2) p5:B(t+2) p6:A0(t+3); vmcnt only at p0 (VWAIT(4)) and p4
// (VWAIT(4); last iter VWAIT(0) since trailing stages are skipped).
// K-accum order ascending => bit-identical to the 2-barrier kernels.
template<bool ISK4>
__global__ __launch_bounds__(512, 1) void gemm8p(const u16* __restrict__ Ap,
                                                 const u16* __restrict__ Bp,
                                                 const float* __restrict__ bias,
                                                 u16* __restrict__ outh,
                                                 float* __restrict__ outf) {
    __shared__ u16 L[3][2][8192];                  // 96 KB
    const int tid = threadIdx.x, lane = tid & 63;
    const int w = tid >> 6, wm = w >> 2, wn = w & 3;
    const int rl = lane & 15, gk = lane >> 4, r4 = gk << 2;
    const int n0 = blockIdx.x << 7, m0 = blockIdx.y << 8;
    const u16* Ab = Ap + (int64_t)m0 * 1024;
    const u16* Bb = Bp + (int64_t)n0 * 1024;
    const int srow0 = tid >> 3, scol = tid & 7;    // LDS dest = wave-uniform + lane*16B
    f32x4 acc[2][4][2] = {};
    bf16x8 afr[4][2];

#define STAGE1(X, KT) do { if ((X) >= 0 && (KT) < 16) {                          \
    const u16* _b = (((X) < 2) ? (Ab + (int64_t)((X) * 128) * 1024) : Bb)        \
                    + (KT) * 64;                                                 \
    u16* _l = &L[((X) < 0) ? 0 : (X)][(KT) & 1][0];                              \
    _Pragma("unroll") for (int _j = 0; _j < 2; ++_j) {                           \
        const int _r = _j * 64 + srow0;                                          \
        const int _g = scol ^ (_r & 7);                                          \
        gld16(_b + (int64_t)_r * 1024 + _g * 8, &_l[_r * 64 + scol * 8]);        \
    } } } while (0)

#define RDF(X, PAR, ROW, KHGK)                                                   \
    (*reinterpret_cast<const bf16x8*>(                                           \
        &L[(X)][(PAR)][(ROW) * 64 + (((KHGK) ^ ((ROW) & 7)) << 3)]))

#define PHASE(QM, QN, PAR, STX, STKT, WMODE) do {                                \
    STAGE1(STX, STKT);                                                           \
    if ((WMODE) == 1) { VWAIT(4); } else if ((WMODE) == 2) { VWAIT(0); }         \
    __builtin_amdgcn_s_barrier(); __builtin_amdgcn_sched_barrier(0);             \
    if ((QN) == 0) {                                                             \
        _Pragma("unroll") for (int _mf = 0; _mf < 4; ++_mf) {                    \
            afr[_mf][0] = RDF(QM, PAR, wm * 64 + _mf * 16 + rl, gk);             \
            afr[_mf][1] = RDF(QM, PAR, wm * 64 + _mf * 16 + rl, 4 + gk);         \
        } }                                                                      \
    bf16x8 _b0 = RDF(2, PAR, (QN) * 64 + wn * 16 + rl, gk);                      \
    bf16x8 _b1 = RDF(2, PAR, (QN) * 64 + wn * 16 + rl, 4 + gk);                  \
    LWAIT; __builtin_amdgcn_sched_barrier(0);                                    \
    __builtin_amdgcn_s_setprio(1);                                               \
    _Pragma("unroll") for (int _mf = 0; _mf < 4; ++_mf) {                        \
        acc[QM][_mf][QN] = __builtin_amdgcn_mfma_f32_16x16x32_bf16(              \
            afr[_mf][0], _b0, acc[QM][_mf][QN], 0, 0, 0);                        \
        acc[QM][_mf][QN] = __builtin_amdgcn_mfma_f32_16x16x32_bf16(              \
            afr[_mf][1], _b1, acc[QM][_mf][QN], 0, 0, 0);                        \
    }                                                                            \
    __builtin_amdgcn_s_setprio(0);                                               \
    __builtin_amdgcn_s_barrier(); __builtin_amdgcn_sched_barrier(0);             \
} while (0)

    // prologue: A0(0), A1(0), B(0), A0(1)
    STAGE1(0, 0); STAGE1(1, 0); STAGE1(2, 0); STAGE1(0, 1);
    for (int i = 0; i < 8; ++i) {
        const int t = 2 * i;
        PHASE(0, 0, 0, 1, t + 1, 1);
        PHASE(0, 1, 0, 2, t + 1, 0);
        PHASE(1, 0, 0, 0, t + 2, 0);
        PHASE(1, 1, 0, -1, 0, 0);
        PHASE(0, 0, 1, 1, t + 2, (i == 7) ? 2 : 1);
        PHASE(0, 1, 1, 2, t + 2, 0);
        PHASE(1, 0, 1, 0, t + 3, 0);
        PHASE(1, 1, 1, -1, 0, 0);
    }
#undef PHASE
#undef RDF
#undef STAGE1
#pragma unroll
    for (int qm = 0; qm < 2; ++qm)
#pragma unroll
        for (int mf = 0; mf < 4; ++mf)
#pragma unroll
            for (int qn = 0; qn < 2; ++qn)
#pragma unroll
                for (int j = 0; j < 4; ++j) {
                    const int row = m0 + qm * 128 + wm * 64 + mf * 16 + r4 + j;
                    const int col = n0 + qn * 64 + wn * 16 + rl;
                    if (ISK4)
                        outf[(int64_t)row * 1024 + col] = acc[qm][mf][qn][j] + bias[col];
                    else
                        outh[(int64_t)row * 3072 + col] = f2bf(acc[qm][mf][qn][j]);
                }
}

// ---------------- K0v: pre-transpose V planes: Vt[z][e 128][kpos 1024]
__global__ __launch_bounds__(256, 2) void k0v_vt(const u16* __restrict__ Qh,
                                                 u16* __restrict__ Vt) {
    __shared__ u16 T[128][144];
    const int tid = threadIdx.x;
    const int z = blockIdx.y, b = z >> 4, h = z & 15;
    const int kt = blockIdx.x;
    const int c0v = (h < 8) ? (1024 + h * 128) : (2048 + (h - 8) * 128);
    const u16* Vbase = Qh + ((int64_t)b * 2048 + 1) * 3072 + c0v;
    const int row = tid >> 1, e0 = (tid & 1) << 6;
    const u16* src = Vbase + (int64_t)(kt * 128 + row) * 6144 + e0;
#pragma unroll
    for (int i = 0; i < 8; ++i) {
        us8 v = *reinterpret_cast<const us8*>(src + i * 8);
#pragma unroll
        for (int j = 0; j < 8; ++j) T[e0 + i * 8 + j][row] = v[j];
    }
    __syncthreads();
    const int e = tid >> 1, k0 = (tid & 1) << 6;
    u16* dst = Vt + ((int64_t)z << 17) + (int64_t)e * 1024 + kt * 128 + k0;
#pragma unroll
    for (int i = 0; i < 8; ++i)
        *reinterpret_cast<us8*>(dst + i * 8) = *reinterpret_cast<const us8*>(&T[e][k0 + i * 8]);
}

// ---------------- K23 v5 (R13 best): exp-once fused attention
__global__ __launch_bounds__(256, 2) void k23_fused(const u16* __restrict__ Qh,
                                                    const u16* __restrict__ Vt,
                                                    float* __restrict__ attn,
                                                    u16* __restrict__ Obf) {
    __shared__ u16 LQ[4096];
    __shared__ u16 LKV[3][8192];
    __shared__ u16 Ph[32 * 72];
    __shared__ float pS[4][32];
    __shared__ float rowInv[32];
    const int tid = threadIdx.x, lane = tid & 63, w = tid >> 6;
    const u32 wgid = blockIdx.x;
    const int xcd = wgid & 7, t0 = wgid >> 3;
    const int mt = t0 & 31, z = ((t0 >> 5) << 3) + xcd;
    const int b = z >> 4, h = z & 15;
    const int m0 = mt << 5;
    const u16* Qbase = Qh + ((int64_t)b * 2048 + 2 * m0) * 3072 + h * 128;
    const int pk  = (h < 8) ? 0 : 1;
    const int c0k = (h < 8) ? (2048 + h * 128) : ((h - 8) * 128);
    const u16* Kbase = Qh + ((int64_t)b * 2048 + pk) * 3072 + c0k;
    const u16* Vtz = Vt + ((int64_t)z << 17);
    float* attnZ = attn + ((int64_t)z << 20) + (int64_t)m0 * 1024;
    const int rl = lane & 15, gk = lane >> 4;
    const int r4 = gk << 2;
    const int sm = w & 1, sn = w >> 1;
    gld_t32x128(Qbase, 6144, LQ, w, lane);
    gld_t64x128(Kbase,             6144, LKV[0], w, lane);
    gld_t64x128(Kbase + 64 * 6144, 6144, LKV[1], w, lane);
    u32 pk0[32], pk1[32];
    float ssum0 = 0.f, ssum1 = 0.f;
#pragma unroll
    for (int t = 0; t < 16; ++t) {
        if (t == 15) { VWAIT(0); } else { VWAIT(4); }
        BARRIER;
        if (t < 14)
            gld_t64x128(Kbase + (int64_t)(t + 2) * 64 * 6144, 6144, LKV[(t + 2) % 3], w, lane);
        f32x4 s0 = {}, s1 = {};
#pragma unroll
        for (int ks = 0; ks < 4; ++ks) {
            bf16x8 kf = *reinterpret_cast<const bf16x8*>(&LKV[t % 3][idxT(w * 16 + rl, ks * 4 + gk)]);
            bf16x8 q0 = *reinterpret_cast<const bf16x8*>(&LQ[idxT(rl, ks * 4 + gk)]);
            bf16x8 q1 = *reinterpret_cast<const bf16x8*>(&LQ[idxT(16 + rl, ks * 4 + gk)]);
            s0 = __builtin_amdgcn_mfma_f32_16x16x32_bf16(kf, q0, s0, 0, 0, 0);
            s1 = __builtin_amdgcn_mfma_f32_16x16x32_bf16(kf, q1, s1, 0, 0, 0);
        }
        float p0[4], p1[4];
#pragma unroll
        for (int j = 0; j < 4; ++j) {
            p0[j] = __expf(s0[j] * 0.125f); ssum0 += p0[j];
            p1[j] = __expf(s1[j] * 0.125f); ssum1 += p1[j];
        }
        pk0[2 * t]     = cvtpk(p0[0], p0[1]);
        pk1[2 * t]     = cvtpk(p0[2], p0[3]);
        pk0[2 * t + 1] = cvtpk(p1[0], p1[1]);
        pk1[2 * t + 1] = cvtpk(p1[2], p1[3]);
    }
    ssum0 += __shfl_xor(ssum0, 16); ssum0 += __shfl_xor(ssum0, 32);
    ssum1 += __shfl_xor(ssum1, 16); ssum1 += __shfl_xor(ssum1, 32);
    if (lane < 16) { pS[w][lane] = ssum0; pS[w][16 + lane] = ssum1; }
    LWAIT; BARRIER;
    gld_v128x64(Vtz,      1024, LKV[0], w, lane);
    gld_v128x64(Vtz + 64, 1024, LKV[1], w, lane);
    if (tid < 32)
        rowInv[tid] = 1.0f / (pS[0][tid] + pS[1][tid] + pS[2][tid] + pS[3][tid]);
    LWAIT; BARRIER;
    const float Iq0 = rowInv[rl], Iq1 = rowInv[16 + rl];
    float IqO[4];
#pragma unroll
    for (int j = 0; j < 4; ++j) IqO[j] = rowInv[sm * 16 + r4 + j];
    f32x4 po[4] = {};
#pragma unroll
    for (int t = 0; t < 16; ++t) {
        if (t == 0)       { VWAIT(4); }
        else if (t == 15) { VWAIT(2); }
        else              { VWAIT(6); }
        BARRIER;
        if (t < 14)
            gld_v128x64(Vtz + (t + 2) * 64, 1024, LKV[(t + 2) % 3], w, lane);
        const u32 a0 = pk0[2 * t], a1 = pk1[2 * t];
        const u32 b0 = pk0[2 * t + 1], b1 = pk1[2 * t + 1];
        *reinterpret_cast<uint2*>(&Ph[rl * 72 + w * 16 + r4])        = make_uint2(a0, a1);
        *reinterpret_cast<uint2*>(&Ph[(16 + rl) * 72 + w * 16 + r4]) = make_uint2(b0, b1);
        *reinterpret_cast<float4*>(&attnZ[(int64_t)rl * 1024 + t * 64 + w * 16 + r4])
            = make_float4(__uint_as_float(a0 << 16) * Iq0,
                          __uint_as_float(a0 & 0xFFFF0000u) * Iq0,
                          __uint_as_float(a1 << 16) * Iq0,
                          __uint_as_float(a1 & 0xFFFF0000u) * Iq0);
        *reinterpret_cast<float4*>(&attnZ[(int64_t)(16 + rl) * 1024 + t * 64 + w * 16 + r4])
            = make_float4(__uint_as_float(b0 << 16) * Iq1,
                          __uint_as_float(b0 & 0xFFFF0000u) * Iq1,
                          __uint_as_float(b1 << 16) * Iq1,
                          __uint_as_float(b1 & 0xFFFF0000u) * Iq1);
        LWAIT; BARRIER;
        bf16x8 pa0 = *reinterpret_cast<const bf16x8*>(&Ph[(sm * 16 + rl) * 72 + gk * 8]);
        bf16x8 pa1 = *reinterpret_cast<const bf16x8*>(&Ph[(sm * 16 + rl) * 72 + 32 + gk * 8]);
#pragma unroll
        for (int n = 0; n < 4; ++n) {
            bf16x8 bv0 = *reinterpret_cast<const bf16x8*>(&LKV[t % 3][idxV(sn * 64 + n * 16 + rl, gk)]);
            bf16x8 bv1 = *reinterpret_cast<const bf16x8*>(&LKV[t % 3][idxV(sn * 64 + n * 16 + rl, 4 + gk)]);
            po[n] = __builtin_amdgcn_mfma_f32_16x16x32_bf16(pa0, bv0, po[n], 0, 0, 0);
            po[n] = __builtin_amdgcn_mfma_f32_16x16x32_bf16(pa1, bv1, po[n], 0, 0, 0);
        }
    }
    const int poh = h >> 3, cb2 = (h & 7) << 7;
#pragma unroll
    for (int n = 0; n < 4; ++n)
#pragma unroll
        for (int j = 0; j < 4; ++j) {
            const int qrow = m0 + sm * 16 + r4 + j;
            Obf[((int64_t)b * 2048 + 2 * qrow + poh) * 1024
                + cb2 + sn * 64 + n * 16 + rl] = f2bf(po[n][j] * IqO[j]);
        }
}

extern "C" void kernel_launch(void* const* d_in, const int* in_sizes, int n_in,
                              void* d_out, int out_size, void* d_ws, size_t ws_size,
                              hipStream_t stream) {
    const float* x     = (const float*)d_in[0];
    const float* ctx   = (const float*)d_in[1];
    const float* wqkv  = (const float*)d_in[2];
    const float* wproj = (const float*)d_in[3];
    const float* bias  = (const float*)d_in[4];
    float* out  = (float*)d_out;                 // [4,2048,1024]
    float* attn = out + 8388608;                 // [4,16,1024,1024] f32

    // ws (u16), total 92.3 MB
    u16* Qh  = (u16*)d_ws;                       // [8192,3072]
    u16* Vt  = Qh + 25165824;                    // [64,128,1024]
    u16* Wh  = Vt + 8388608;                     // [3072,1024]
    u16* Phw = Wh + 3145728;                     // [1024,1024]
    u16* Obf = Phw + 1048576;                    // [8192,1024]

    // X bf16 plane parked in the attn region (dead once k1 finishes)
    u16* Xh = (u16*)attn;                        // [8192,1024]

    k0_all        <<<dim3(6144),   256, 0, stream>>>(wqkv, x, ctx, wproj, Wh, Xh, Phw);
    gemm8p<false> <<<dim3(24, 32), 512, 0, stream>>>(Xh, Wh, nullptr, Qh, nullptr);
    k0v_vt        <<<dim3(8, 64),  256, 0, stream>>>(Qh, Vt);
    k23_fused     <<<dim3(2048),   256, 0, stream>>>(Qh, Vt, attn, Obf);
    gemm8p<true>  <<<dim3(8, 32),  512, 0, stream>>>(Obf, Phw, bias, nullptr, out);
}

// Round 18
// 204.892 us; speedup vs baseline: 1.4377x; 1.1313x over previous
//
#include <hip/hip_runtime.h>
#include <stdint.h>

typedef short bf16x8 __attribute__((ext_vector_type(8)));
typedef unsigned short us8 __attribute__((ext_vector_type(8)));
typedef float f32x4 __attribute__((ext_vector_type(4)));
typedef unsigned short u16;
typedef unsigned int u32;

__device__ __forceinline__ u16 f2bf(float f) {
    u32 u = __float_as_uint(f);
    return (u16)((u + 0x7FFFu + ((u >> 16) & 1u)) >> 16);   // RNE
}

__device__ __forceinline__ u32 cvtpk(float lo, float hi) {   // D.lo=bf16(lo), D.hi=bf16(hi)
    u32 r;
    asm("v_cvt_pk_bf16_f32 %0, %1, %2" : "=v"(r) : "v"(lo), "v"(hi));
    return r;
}

typedef __attribute__((address_space(3))) unsigned int lds_uint;
typedef const __attribute__((address_space(1))) unsigned int glb_uint;
__device__ __forceinline__ void gld16(const void* g, void* l) {
    __builtin_amdgcn_global_load_lds((glb_uint*)g, (lds_uint*)l, 16, 0, 0);
}

#define VWAIT(n) asm volatile("s_waitcnt vmcnt(" #n ") lgkmcnt(0)" ::: "memory")
#define LWAIT    asm volatile("s_waitcnt lgkmcnt(0)" ::: "memory")
#define BARRIER  do { __builtin_amdgcn_s_barrier(); __builtin_amdgcn_sched_barrier(0); } while (0)

// ---- swizzled staging (rule #21), 8-wave/512-thread variants (R12-verified) ----

// [64 rows][128 cols] bf16 tile; slot = g ^ (row&7)  (2 gld16/thread)
__device__ __forceinline__ void gld8_t64x128(const u16* __restrict__ g, int64_t stride,
                                             u16* lds, int w, int lane) {
#pragma unroll
    for (int i = 0; i < 2; ++i) {
        const int gg = w * 2 + i;                     // 0..15 -> rows gg*4..+3
        const int row = gg * 4 + (lane >> 4);
        const int gs = (lane & 15) ^ (row & 7);
        gld16(g + (int64_t)row * stride + (gs << 3), &lds[gg * 512]);
    }
}
__device__ __forceinline__ int idxT(int row, int gk) {    // [*][128] read
    return row * 128 + ((gk ^ (row & 7)) << 3);
}

// [128 rows][64 cols] bf16 tile (V^T chunk); slot = g3 ^ (row&7)  (2 gld16/thread)
__device__ __forceinline__ void gld8_v128x64(const u16* __restrict__ g, int64_t stride,
                                             u16* lds, int w, int lane) {
#pragma unroll
    for (int i = 0; i < 2; ++i) {
        const int seg = w * 2 + i;                    // 0..15 -> rows seg*8..+7
        const int row = seg * 8 + (lane >> 3);
        const int gs = (lane & 7) ^ (row & 7);
        gld16(g + (int64_t)row * stride + (gs << 3), &lds[seg * 512]);
    }
}
__device__ __forceinline__ int idxV(int row, int g3) {    // [128][64] read
    return row * 64 + ((g3 ^ (row & 7)) << 3);
}

// ---------------- K0: all four f32->bf16 conversions in one launch
__global__ void k0_all(const float* __restrict__ wqkv, const float* __restrict__ x,
                       const float* __restrict__ ctx, const float* __restrict__ wproj,
                       u16* __restrict__ Wh, u16* __restrict__ Xh,
                       u16* __restrict__ Phw) {
    const int gid = blockIdx.x;
    const float* src; u16* dst; int mode; int lg;
    if (gid < 1536)      { src = wqkv;  dst = Wh;  mode = 0; lg = gid; }
    else if (gid < 3584) { src = x;     dst = Xh;  mode = 1; lg = gid - 1536; }
    else if (gid < 5632) { src = ctx;   dst = Xh;  mode = 2; lg = gid - 3584; }
    else                 { src = wproj; dst = Phw; mode = 0; lg = gid - 5632; }
    const int64_t base = ((int64_t)lg * 256 + threadIdx.x) * 8;
    const int row = (int)(base >> 10), col = (int)(base & 1023);
    int orow = row;
    if (mode == 1) orow = row + ((row >> 10) << 10);
    else if (mode == 2) orow = row + (((row >> 10) + 1) << 10);
    const float4* sp = reinterpret_cast<const float4*>(src + base);
    float4 a = sp[0], b = sp[1];
    float v[8] = {a.x, a.y, a.z, a.w, b.x, b.y, b.z, b.w};
    us8 hh;
#pragma unroll
    for (int j = 0; j < 8; ++j) hh[j] = f2bf(v[j]);
    *reinterpret_cast<us8*>(&dst[(int64_t)orow * 1024 + col]) = hh;
}

// ---------------- 8-phase GEMM template (R17 proven), BM=256 x BN=128 x BK=64
template<bool ISK4>
__global__ __launch_bounds__(512, 1) void gemm8p(const u16* __restrict__ Ap,
                                                 const u16* __restrict__ Bp,
                                                 const float* __restrict__ bias,
                                                 u16* __restrict__ outh,
                                                 float* __restrict__ outf) {
    __shared__ u16 L[3][2][8192];                  // 96 KB
    const int tid = threadIdx.x, lane = tid & 63;
    const int w = tid >> 6, wm = w >> 2, wn = w & 3;
    const int rl = lane & 15, gk = lane >> 4, r4 = gk << 2;
    const int n0 = blockIdx.x << 7, m0 = blockIdx.y << 8;
    const u16* Ab = Ap + (int64_t)m0 * 1024;
    const u16* Bb = Bp + (int64_t)n0 * 1024;
    const int srow0 = tid >> 3, scol = tid & 7;
    f32x4 acc[2][4][2] = {};
    bf16x8 afr[4][2];

#define STAGE1(X, KT) do { if ((X) >= 0 && (KT) < 16) {                          \
    const u16* _b = (((X) < 2) ? (Ab + (int64_t)((X) * 128) * 1024) : Bb)        \
                    + (KT) * 64;                                                 \
    u16* _l = &L[((X) < 0) ? 0 : (X)][(KT) & 1][0];                              \
    _Pragma("unroll") for (int _j = 0; _j < 2; ++_j) {                           \
        const int _r = _j * 64 + srow0;                                          \
        const int _g = scol ^ (_r & 7);                                          \
        gld16(_b + (int64_t)_r * 1024 + _g * 8, &_l[_r * 64 + scol * 8]);        \
    } } } while (0)

#define RDF(X, PAR, ROW, KHGK)                                                   \
    (*reinterpret_cast<const bf16x8*>(                                           \
        &L[(X)][(PAR)][(ROW) * 64 + (((KHGK) ^ ((ROW) & 7)) << 3)]))

#define PHASE(QM, QN, PAR, STX, STKT, WMODE) do {                                \
    STAGE1(STX, STKT);                                                           \
    if ((WMODE) == 1) { VWAIT(4); } else if ((WMODE) == 2) { VWAIT(0); }         \
    __builtin_amdgcn_s_barrier(); __builtin_amdgcn_sched_barrier(0);             \
    if ((QN) == 0) {                                                             \
        _Pragma("unroll") for (int _mf = 0; _mf < 4; ++_mf) {                    \
            afr[_mf][0] = RDF(QM, PAR, wm * 64 + _mf * 16 + rl, gk);             \
            afr[_mf][1] = RDF(QM, PAR, wm * 64 + _mf * 16 + rl, 4 + gk);         \
        } }                                                                      \
    bf16x8 _b0 = RDF(2, PAR, (QN) * 64 + wn * 16 + rl, gk);                      \
    bf16x8 _b1 = RDF(2, PAR, (QN) * 64 + wn * 16 + rl, 4 + gk);                  \
    LWAIT; __builtin_amdgcn_sched_barrier(0);                                    \
    __builtin_amdgcn_s_setprio(1);                                               \
    _Pragma("unroll") for (int _mf = 0; _mf < 4; ++_mf) {                        \
        acc[QM][_mf][QN] = __builtin_amdgcn_mfma_f32_16x16x32_bf16(              \
            afr[_mf][0], _b0, acc[QM][_mf][QN], 0, 0, 0);                        \
        acc[QM][_mf][QN] = __builtin_amdgcn_mfma_f32_16x16x32_bf16(              \
            afr[_mf][1], _b1, acc[QM][_mf][QN], 0, 0, 0);                        \
    }                                                                            \
    __builtin_amdgcn_s_setprio(0);                                               \
    __builtin_amdgcn_s_barrier(); __builtin_amdgcn_sched_barrier(0);             \
} while (0)

    STAGE1(0, 0); STAGE1(1, 0); STAGE1(2, 0); STAGE1(0, 1);
    for (int i = 0; i < 8; ++i) {
        const int t = 2 * i;
        PHASE(0, 0, 0, 1, t + 1, 1);
        PHASE(0, 1, 0, 2, t + 1, 0);
        PHASE(1, 0, 0, 0, t + 2, 0);
        PHASE(1, 1, 0, -1, 0, 0);
        PHASE(0, 0, 1, 1, t + 2, (i == 7) ? 2 : 1);
        PHASE(0, 1, 1, 2, t + 2, 0);
        PHASE(1, 0, 1, 0, t + 3, 0);
        PHASE(1, 1, 1, -1, 0, 0);
    }
#undef PHASE
#undef RDF
#undef STAGE1
#pragma unroll
    for (int qm = 0; qm < 2; ++qm)
#pragma unroll
        for (int mf = 0; mf < 4; ++mf)
#pragma unroll
            for (int qn = 0; qn < 2; ++qn)
#pragma unroll
                for (int j = 0; j < 4; ++j) {
                    const int row = m0 + qm * 128 + wm * 64 + mf * 16 + r4 + j;
                    const int col = n0 + qn * 64 + wn * 16 + rl;
                    if (ISK4)
                        outf[(int64_t)row * 1024 + col] = acc[qm][mf][qn][j] + bias[col];
                    else
                        outh[(int64_t)row * 3072 + col] = f2bf(acc[qm][mf][qn][j]);
                }
}

// ---------------- K0v: pre-transpose V planes: Vt[z][e 128][kpos 1024]
__global__ __launch_bounds__(256, 2) void k0v_vt(const u16* __restrict__ Qh,
                                                 u16* __restrict__ Vt) {
    __shared__ u16 T[128][144];
    const int tid = threadIdx.x;
    const int z = blockIdx.y, b = z >> 4, h = z & 15;
    const int kt = blockIdx.x;
    const int c0v = (h < 8) ? (1024 + h * 128) : (2048 + (h - 8) * 128);
    const u16* Vbase = Qh + ((int64_t)b * 2048 + 1) * 3072 + c0v;
    const int row = tid >> 1, e0 = (tid & 1) << 6;
    const u16* src = Vbase + (int64_t)(kt * 128 + row) * 6144 + e0;
#pragma unroll
    for (int i = 0; i < 8; ++i) {
        us8 v = *reinterpret_cast<const us8*>(src + i * 8);
#pragma unroll
        for (int j = 0; j < 8; ++j) T[e0 + i * 8 + j][row] = v[j];
    }
    __syncthreads();
    const int e = tid >> 1, k0 = (tid & 1) << 6;
    u16* dst = Vt + ((int64_t)z << 17) + (int64_t)e * 1024 + kt * 128 + k0;
#pragma unroll
    for (int i = 0; i < 8; ++i)
        *reinterpret_cast<us8*>(dst + i * 8) = *reinterpret_cast<const us8*>(&T[e][k0 + i * 8]);
}

// ---------------- K23 v8: v5 structure with QBLK=64, 512 thr (8 waves).
// QK^T waves: (kt = w&3 k-tile, qh = w>>2 q-half); Ph LDS decouples PV
// wave-assignment (qq = w&3 q-tile, sv = w>>2 e-half) — per-thread state
// unchanged vs v5 (64 packed u32). K/V L2 traffic per z halves; 16 waves/CU.
// vmcnt re-derived for 2-op stages + 2-op store batches.
__global__ __launch_bounds__(512, 4) void k23_fused(const u16* __restrict__ Qh,
                                                    const u16* __restrict__ Vt,
                                                    float* __restrict__ attn,
                                                    u16* __restrict__ Obf) {
    __shared__ u16 LQ[8192];                         // 64x128
    __shared__ u16 LKV[3][8192];                     // 3 x (64x128 K | 128x64 V^T)
    __shared__ u16 Ph[64 * 72];                      // p~ bf16 [q][k] (+pad)
    __shared__ float pS[8][32];
    __shared__ float rowInv[64];
    const int tid = threadIdx.x, lane = tid & 63, w = tid >> 6;
    const u32 wgid = blockIdx.x;
    const int xcd = wgid & 7, t0 = wgid >> 3;        // T1: same-z -> same XCD
    const int mt = t0 & 15, z = ((t0 >> 4) << 3) + xcd;
    const int b = z >> 4, h = z & 15;
    const int m0 = mt << 6;                          // 64 q-rows per block
    const int kt = w & 3, qh = w >> 2;               // QK^T roles
    const int qq = w & 3, sv = w >> 2;               // PV roles
    const int rl = lane & 15, gk = lane >> 4, r4 = gk << 2;
    const u16* Qbase = Qh + ((int64_t)b * 2048 + 2 * m0) * 3072 + h * 128;
    const int pk  = (h < 8) ? 0 : 1;
    const int c0k = (h < 8) ? (2048 + h * 128) : ((h - 8) * 128);
    const u16* Kbase = Qh + ((int64_t)b * 2048 + pk) * 3072 + c0k;
    const u16* Vtz = Vt + ((int64_t)z << 17);
    float* attnZ = attn + ((int64_t)z << 20) + (int64_t)m0 * 1024;
    gld8_t64x128(Qbase, 6144, LQ, w, lane);          // Q 64x128 (2 ops)
    gld8_t64x128(Kbase,             6144, LKV[0], w, lane);
    gld8_t64x128(Kbase + 64 * 6144, 6144, LKV[1], w, lane);
    // ---- pass 1: swapped mfma(K,Q) -> s, exp-once -> packed p~ + running sums
    // pk0/pk1[2t+T]: q = qh*32 + T*16 + rl, k = t*64 + kt*16 + {r4..r4+3}
    u32 pk0[32], pk1[32];
    float ssum0 = 0.f, ssum1 = 0.f;
#pragma unroll
    for (int t = 0; t < 16; ++t) {
        if (t == 15) { VWAIT(0); } else { VWAIT(2); }   // K(t) landed; K(t+1) in flight
        BARRIER;
        if (t < 14)
            gld8_t64x128(Kbase + (int64_t)(t + 2) * 64 * 6144, 6144, LKV[(t + 2) % 3], w, lane);
        f32x4 s0 = {}, s1 = {};
#pragma unroll
        for (int ks = 0; ks < 4; ++ks) {
            bf16x8 kf = *reinterpret_cast<const bf16x8*>(&LKV[t % 3][idxT(kt * 16 + rl, ks * 4 + gk)]);
            bf16x8 q0 = *reinterpret_cast<const bf16x8*>(&LQ[idxT(qh * 32 + rl, ks * 4 + gk)]);
            bf16x8 q1 = *reinterpret_cast<const bf16x8*>(&LQ[idxT(qh * 32 + 16 + rl, ks * 4 + gk)]);
            s0 = __builtin_amdgcn_mfma_f32_16x16x32_bf16(kf, q0, s0, 0, 0, 0);
            s1 = __builtin_amdgcn_mfma_f32_16x16x32_bf16(kf, q1, s1, 0, 0, 0);
        }
        float p0[4], p1[4];
#pragma unroll
        for (int j = 0; j < 4; ++j) {
            p0[j] = __expf(s0[j] * 0.125f); ssum0 += p0[j];
            p1[j] = __expf(s1[j] * 0.125f); ssum1 += p1[j];
        }
        pk0[2 * t]     = cvtpk(p0[0], p0[1]);
        pk1[2 * t]     = cvtpk(p0[2], p0[3]);
        pk0[2 * t + 1] = cvtpk(p1[0], p1[1]);
        pk1[2 * t + 1] = cvtpk(p1[2], p1[3]);
    }
    // ---- stats: reduce over gk groups, then over the 4 kt-waves per q-half
    ssum0 += __shfl_xor(ssum0, 16); ssum0 += __shfl_xor(ssum0, 32);
    ssum1 += __shfl_xor(ssum1, 16); ssum1 += __shfl_xor(ssum1, 32);
    if (lane < 16) { pS[w][lane] = ssum0; pS[w][16 + lane] = ssum1; }
    LWAIT; BARRIER;                                  // all K readers done; buf0/1 free
    gld8_v128x64(Vtz,      1024, LKV[0], w, lane);   // V chunks 0,1 overlap stats
    gld8_v128x64(Vtz + 64, 1024, LKV[1], w, lane);
    if (tid < 64) {
        const int qb = (tid >> 5) << 2;              // q-half -> wave group base
        rowInv[tid] = 1.0f / (pS[qb][tid & 31] + pS[qb + 1][tid & 31]
                              + pS[qb + 2][tid & 31] + pS[qb + 3][tid & 31]);
    }
    LWAIT; BARRIER;
    const float Iq0 = rowInv[qh * 32 + rl], Iq1 = rowInv[qh * 32 + 16 + rl];
    float IqO[4];
#pragma unroll
    for (int j = 0; j < 4; ++j) IqO[j] = rowInv[qq * 16 + r4 + j];
    // ---- pass 2: Ph <- packed; attn <- shift-unpack * Iq; PV over full chunk
    f32x4 po[4] = {};
#pragma unroll
    for (int t = 0; t < 16; ++t) {
        if (t == 0)       { VWAIT(2); }              // V0 landed; V1 in flight
        else if (t == 1)  { VWAIT(4); }              // V1 landed; V2+st0 fly
        else if (t == 15) { VWAIT(4); }              // V15 landed; st13+st14 fly
        else              { VWAIT(6); }              // V(t) landed; st+V+st fly
        BARRIER;
        if (t < 14)
            gld8_v128x64(Vtz + (t + 2) * 64, 1024, LKV[(t + 2) % 3], w, lane);
        const u32 a0 = pk0[2 * t], a1 = pk1[2 * t];
        const u32 b0 = pk0[2 * t + 1], b1 = pk1[2 * t + 1];
        *reinterpret_cast<uint2*>(&Ph[(qh * 32 + rl) * 72 + kt * 16 + r4])
            = make_uint2(a0, a1);
        *reinterpret_cast<uint2*>(&Ph[(qh * 32 + 16 + rl) * 72 + kt * 16 + r4])
            = make_uint2(b0, b1);
        *reinterpret_cast<float4*>(&attnZ[(int64_t)(qh * 32 + rl) * 1024 + t * 64 + kt * 16 + r4])
            = make_float4(__uint_as_float(a0 << 16) * Iq0,
                          __uint_as_float(a0 & 0xFFFF0000u) * Iq0,
                          __uint_as_float(a1 << 16) * Iq0,
                          __uint_as_float(a1 & 0xFFFF0000u) * Iq0);
        *reinterpret_cast<float4*>(&attnZ[(int64_t)(qh * 32 + 16 + rl) * 1024 + t * 64 + kt * 16 + r4])
            = make_float4(__uint_as_float(b0 << 16) * Iq1,
                          __uint_as_float(b0 & 0xFFFF0000u) * Iq1,
                          __uint_as_float(b1 << 16) * Iq1,
                          __uint_as_float(b1 & 0xFFFF0000u) * Iq1);
        LWAIT; BARRIER;                              // Ph visible (stores NOT drained)
        bf16x8 pa0 = *reinterpret_cast<const bf16x8*>(&Ph[(qq * 16 + rl) * 72 + gk * 8]);
        bf16x8 pa1 = *reinterpret_cast<const bf16x8*>(&Ph[(qq * 16 + rl) * 72 + 32 + gk * 8]);
#pragma unroll
        for (int n = 0; n < 4; ++n) {
            bf16x8 bv0 = *reinterpret_cast<const bf16x8*>(&LKV[t % 3][idxV(sv * 64 + n * 16 + rl, gk)]);
            bf16x8 bv1 = *reinterpret_cast<const bf16x8*>(&LKV[t % 3][idxV(sv * 64 + n * 16 + rl, 4 + gk)]);
            po[n] = __builtin_amdgcn_mfma_f32_16x16x32_bf16(pa0, bv0, po[n], 0, 0, 0);
            po[n] = __builtin_amdgcn_mfma_f32_16x16x32_bf16(pa1, bv1, po[n], 0, 0, 0);
        }
    }
    // ---- epilogue: O normalize + scatter
    const int poh = h >> 3, cb2 = (h & 7) << 7;
#pragma unroll
    for (int n = 0; n < 4; ++n)
#pragma unroll
        for (int j = 0; j < 4; ++j) {
            const int qrow = m0 + qq * 16 + r4 + j;
            Obf[((int64_t)b * 2048 + 2 * qrow + poh) * 1024
                + cb2 + sv * 64 + n * 16 + rl] = f2bf(po[n][j] * IqO[j]);
        }
}

extern "C" void kernel_launch(void* const* d_in, const int* in_sizes, int n_in,
                              void* d_out, int out_size, void* d_ws, size_t ws_size,
                              hipStream_t stream) {
    const float* x     = (const float*)d_in[0];
    const float* ctx   = (const float*)d_in[1];
    const float* wqkv  = (const float*)d_in[2];
    const float* wproj = (const float*)d_in[3];
    const float* bias  = (const float*)d_in[4];
    float* out  = (float*)d_out;                 // [4,2048,1024]
    float* attn = out + 8388608;                 // [4,16,1024,1024] f32

    // ws (u16), total 92.3 MB
    u16* Qh  = (u16*)d_ws;                       // [8192,3072]
    u16* Vt  = Qh + 25165824;                    // [64,128,1024]
    u16* Wh  = Vt + 8388608;                     // [3072,1024]
    u16* Phw = Wh + 3145728;                     // [1024,1024]
    u16* Obf = Phw + 1048576;                    // [8192,1024]

    // X bf16 plane parked in the attn region (dead once k1 finishes)
    u16* Xh = (u16*)attn;                        // [8192,1024]

    k0_all        <<<dim3(6144),   256, 0, stream>>>(wqkv, x, ctx, wproj, Wh, Xh, Phw);
    gemm8p<false> <<<dim3(24, 32), 512, 0, stream>>>(Xh, Wh, nullptr, Qh, nullptr);
    k0v_vt        <<<dim3(8, 64),  256, 0, stream>>>(Qh, Vt);
    k23_fused     <<<dim3(1024),   512, 0, stream>>>(Qh, Vt, attn, Obf);
    gemm8p<true>  <<<dim3(8, 32),  512, 0, stream>>>(Obf, Phw, bias, nullptr, out);
}

// Round 19
// 195.928 us; speedup vs baseline: 1.5035x; 1.0458x over previous
//
#include <hip/hip_runtime.h>
#include <stdint.h>

typedef short bf16x8 __attribute__((ext_vector_type(8)));
typedef unsigned short us8 __attribute__((ext_vector_type(8)));
typedef float f32x4 __attribute__((ext_vector_type(4)));
typedef unsigned short u16;
typedef unsigned int u32;

__device__ __forceinline__ u16 f2bf(float f) {
    u32 u = __float_as_uint(f);
    return (u16)((u + 0x7FFFu + ((u >> 16) & 1u)) >> 16);   // RNE
}

__device__ __forceinline__ u32 cvtpk(float lo, float hi) {   // D.lo=bf16(lo), D.hi=bf16(hi)
    u32 r;
    asm("v_cvt_pk_bf16_f32 %0, %1, %2" : "=v"(r) : "v"(lo), "v"(hi));
    return r;
}

typedef __attribute__((address_space(3))) unsigned int lds_uint;
typedef const __attribute__((address_space(1))) unsigned int glb_uint;
__device__ __forceinline__ void gld16(const void* g, void* l) {
    __builtin_amdgcn_global_load_lds((glb_uint*)g, (lds_uint*)l, 16, 0, 0);
}

#define VWAIT(n) asm volatile("s_waitcnt vmcnt(" #n ") lgkmcnt(0)" ::: "memory")
#define LWAIT    asm volatile("s_waitcnt lgkmcnt(0)" ::: "memory")
#define BARRIER  do { __builtin_amdgcn_s_barrier(); __builtin_amdgcn_sched_barrier(0); } while (0)

// ---- swizzled staging (rule #21), 8-wave/512-thread variants (R12-verified) ----

// [64 rows][128 cols] bf16 tile; slot = g ^ (row&7)  (2 gld16/thread)
__device__ __forceinline__ void gld8_t64x128(const u16* __restrict__ g, int64_t stride,
                                             u16* lds, int w, int lane) {
#pragma unroll
    for (int i = 0; i < 2; ++i) {
        const int gg = w * 2 + i;                     // 0..15 -> rows gg*4..+3
        const int row = gg * 4 + (lane >> 4);
        const int gs = (lane & 15) ^ (row & 7);
        gld16(g + (int64_t)row * stride + (gs << 3), &lds[gg * 512]);
    }
}
__device__ __forceinline__ int idxT(int row, int gk) {    // [*][128] read
    return row * 128 + ((gk ^ (row & 7)) << 3);
}

// [128 rows][64 cols] bf16 tile (V^T chunk); slot = g3 ^ (row&7)  (2 gld16/thread)
__device__ __forceinline__ void gld8_v128x64(const u16* __restrict__ g, int64_t stride,
                                             u16* lds, int w, int lane) {
#pragma unroll
    for (int i = 0; i < 2; ++i) {
        const int seg = w * 2 + i;                    // 0..15 -> rows seg*8..+7
        const int row = seg * 8 + (lane >> 3);
        const int gs = (lane & 7) ^ (row & 7);
        gld16(g + (int64_t)row * stride + (gs << 3), &lds[seg * 512]);
    }
}
__device__ __forceinline__ int idxV(int row, int g3) {    // [128][64] read
    return row * 64 + ((g3 ^ (row & 7)) << 3);
}

// ---------------- K0: all four f32->bf16 conversions in one launch
__global__ void k0_all(const float* __restrict__ wqkv, const float* __restrict__ x,
                       const float* __restrict__ ctx, const float* __restrict__ wproj,
                       u16* __restrict__ Wh, u16* __restrict__ Xh,
                       u16* __restrict__ Phw) {
    const int gid = blockIdx.x;
    const float* src; u16* dst; int mode; int lg;
    if (gid < 1536)      { src = wqkv;  dst = Wh;  mode = 0; lg = gid; }
    else if (gid < 3584) { src = x;     dst = Xh;  mode = 1; lg = gid - 1536; }
    else if (gid < 5632) { src = ctx;   dst = Xh;  mode = 2; lg = gid - 3584; }
    else                 { src = wproj; dst = Phw; mode = 0; lg = gid - 5632; }
    const int64_t base = ((int64_t)lg * 256 + threadIdx.x) * 8;
    const int row = (int)(base >> 10), col = (int)(base & 1023);
    int orow = row;
    if (mode == 1) orow = row + ((row >> 10) << 10);
    else if (mode == 2) orow = row + (((row >> 10) + 1) << 10);
    const float4* sp = reinterpret_cast<const float4*>(src + base);
    float4 a = sp[0], b = sp[1];
    float v[8] = {a.x, a.y, a.z, a.w, b.x, b.y, b.z, b.w};
    us8 hh;
#pragma unroll
    for (int j = 0; j < 8; ++j) hh[j] = f2bf(v[j]);
    *reinterpret_cast<us8*>(&dst[(int64_t)orow * 1024 + col]) = hh;
}

// ---------------- 8-phase GEMM template (R17 proven), BM=256 x BN=128 x BK=64.
// 1D grid with T1 XCD swizzle: each XCD owns 4 contiguous m-rows x all n
// (its 4 A-panels = 2 MB fit the 4 MB per-XCD L2). NBX = blocks along n.
// Pure index remap vs R17 — bit-identical outputs.
template<bool ISK4, int NBX>
__global__ __launch_bounds__(512, 1) void gemm8p(const u16* __restrict__ Ap,
                                                 const u16* __restrict__ Bp,
                                                 const float* __restrict__ bias,
                                                 u16* __restrict__ outh,
                                                 float* __restrict__ outf) {
    __shared__ u16 L[3][2][8192];                  // 96 KB
    const int tid = threadIdx.x, lane = tid & 63;
    const int w = tid >> 6, wm = w >> 2, wn = w & 3;
    const int rl = lane & 15, gk = lane >> 4, r4 = gk << 2;
    const u32 wgid = blockIdx.x;
    const int xcd = wgid & 7, t6 = wgid >> 3;      // T1: 4 m-rows per XCD chunk
    const int by = xcd * 4 + t6 / NBX, bx = t6 % NBX;
    const int n0 = bx << 7, m0 = by << 8;
    const u16* Ab = Ap + (int64_t)m0 * 1024;
    const u16* Bb = Bp + (int64_t)n0 * 1024;
    const int srow0 = tid >> 3, scol = tid & 7;
    f32x4 acc[2][4][2] = {};
    bf16x8 afr[4][2];

#define STAGE1(X, KT) do { if ((X) >= 0 && (KT) < 16) {                          \
    const u16* _b = (((X) < 2) ? (Ab + (int64_t)((X) * 128) * 1024) : Bb)        \
                    + (KT) * 64;                                                 \
    u16* _l = &L[((X) < 0) ? 0 : (X)][(KT) & 1][0];                              \
    _Pragma("unroll") for (int _j = 0; _j < 2; ++_j) {                           \
        const int _r = _j * 64 + srow0;                                          \
        const int _g = scol ^ (_r & 7);                                          \
        gld16(_b + (int64_t)_r * 1024 + _g * 8, &_l[_r * 64 + scol * 8]);        \
    } } } while (0)

#define RDF(X, PAR, ROW, KHGK)                                                   \
    (*reinterpret_cast<const bf16x8*>(                                           \
        &L[(X)][(PAR)][(ROW) * 64 + (((KHGK) ^ ((ROW) & 7)) << 3)]))

#define PHASE(QM, QN, PAR, STX, STKT, WMODE) do {                                \
    STAGE1(STX, STKT);                                                           \
    if ((WMODE) == 1) { VWAIT(4); } else if ((WMODE) == 2) { VWAIT(0); }         \
    __builtin_amdgcn_s_barrier(); __builtin_amdgcn_sched_barrier(0);             \
    if ((QN) == 0) {                                                             \
        _Pragma("unroll") for (int _mf = 0; _mf < 4; ++_mf) {                    \
            afr[_mf][0] = RDF(QM, PAR, wm * 64 + _mf * 16 + rl, gk);             \
            afr[_mf][1] = RDF(QM, PAR, wm * 64 + _mf * 16 + rl, 4 + gk);         \
        } }                                                                      \
    bf16x8 _b0 = RDF(2, PAR, (QN) * 64 + wn * 16 + rl, gk);                      \
    bf16x8 _b1 = RDF(2, PAR, (QN) * 64 + wn * 16 + rl, 4 + gk);                  \
    LWAIT; __builtin_amdgcn_sched_barrier(0);                                    \
    __builtin_amdgcn_s_setprio(1);                                               \
    _Pragma("unroll") for (int _mf = 0; _mf < 4; ++_mf) {                        \
        acc[QM][_mf][QN] = __builtin_amdgcn_mfma_f32_16x16x32_bf16(              \
            afr[_mf][0], _b0, acc[QM][_mf][QN], 0, 0, 0);                        \
        acc[QM][_mf][QN] = __builtin_amdgcn_mfma_f32_16x16x32_bf16(              \
            afr[_mf][1], _b1, acc[QM][_mf][QN], 0, 0, 0);                        \
    }                                                                            \
    __builtin_amdgcn_s_setprio(0);                                               \
    __builtin_amdgcn_s_barrier(); __builtin_amdgcn_sched_barrier(0);             \
} while (0)

    STAGE1(0, 0); STAGE1(1, 0); STAGE1(2, 0); STAGE1(0, 1);
    for (int i = 0; i < 8; ++i) {
        const int t = 2 * i;
        PHASE(0, 0, 0, 1, t + 1, 1);
        PHASE(0, 1, 0, 2, t + 1, 0);
        PHASE(1, 0, 0, 0, t + 2, 0);
        PHASE(1, 1, 0, -1, 0, 0);
        PHASE(0, 0, 1, 1, t + 2, (i == 7) ? 2 : 1);
        PHASE(0, 1, 1, 2, t + 2, 0);
        PHASE(1, 0, 1, 0, t + 3, 0);
        PHASE(1, 1, 1, -1, 0, 0);
    }
#undef PHASE
#undef RDF
#undef STAGE1
#pragma unroll
    for (int qm = 0; qm < 2; ++qm)
#pragma unroll
        for (int mf = 0; mf < 4; ++mf)
#pragma unroll
            for (int qn = 0; qn < 2; ++qn)
#pragma unroll
                for (int j = 0; j < 4; ++j) {
                    const int row = m0 + qm * 128 + wm * 64 + mf * 16 + r4 + j;
                    const int col = n0 + qn * 64 + wn * 16 + rl;
                    if (ISK4)
                        outf[(int64_t)row * 1024 + col] = acc[qm][mf][qn][j] + bias[col];
                    else
                        outh[(int64_t)row * 3072 + col] = f2bf(acc[qm][mf][qn][j]);
                }
}

// ---------------- K0v: pre-transpose V planes: Vt[z][e 128][kpos 1024]
__global__ __launch_bounds__(256, 2) void k0v_vt(const u16* __restrict__ Qh,
                                                 u16* __restrict__ Vt) {
    __shared__ u16 T[128][144];
    const int tid = threadIdx.x;
    const int z = blockIdx.y, b = z >> 4, h = z & 15;
    const int kt = blockIdx.x;
    const int c0v = (h < 8) ? (1024 + h * 128) : (2048 + (h - 8) * 128);
    const u16* Vbase = Qh + ((int64_t)b * 2048 + 1) * 3072 + c0v;
    const int row = tid >> 1, e0 = (tid & 1) << 6;
    const u16* src = Vbase + (int64_t)(kt * 128 + row) * 6144 + e0;
#pragma unroll
    for (int i = 0; i < 8; ++i) {
        us8 v = *reinterpret_cast<const us8*>(src + i * 8);
#pragma unroll
        for (int j = 0; j < 8; ++j) T[e0 + i * 8 + j][row] = v[j];
    }
    __syncthreads();
    const int e = tid >> 1, k0 = (tid & 1) << 6;
    u16* dst = Vt + ((int64_t)z << 17) + (int64_t)e * 1024 + kt * 128 + k0;
#pragma unroll
    for (int i = 0; i < 8; ++i)
        *reinterpret_cast<us8*>(dst + i * 8) = *reinterpret_cast<const us8*>(&T[e][k0 + i * 8]);
}

// ---------------- K23 v8 (R18 proven): QBLK=64, 512 thr (8 waves)
__global__ __launch_bounds__(512, 4) void k23_fused(const u16* __restrict__ Qh,
                                                    const u16* __restrict__ Vt,
                                                    float* __restrict__ attn,
                                                    u16* __restrict__ Obf) {
    __shared__ u16 LQ[8192];                         // 64x128
    __shared__ u16 LKV[3][8192];                     // 3 x (64x128 K | 128x64 V^T)
    __shared__ u16 Ph[64 * 72];                      // p~ bf16 [q][k] (+pad)
    __shared__ float pS[8][32];
    __shared__ float rowInv[64];
    const int tid = threadIdx.x, lane = tid & 63, w = tid >> 6;
    const u32 wgid = blockIdx.x;
    const int xcd = wgid & 7, t0 = wgid >> 3;        // T1: same-z -> same XCD
    const int mt = t0 & 15, z = ((t0 >> 4) << 3) + xcd;
    const int b = z >> 4, h = z & 15;
    const int m0 = mt << 6;                          // 64 q-rows per block
    const int kt = w & 3, qh = w >> 2;               // QK^T roles
    const int qq = w & 3, sv = w >> 2;               // PV roles
    const int rl = lane & 15, gk = lane >> 4, r4 = gk << 2;
    const u16* Qbase = Qh + ((int64_t)b * 2048 + 2 * m0) * 3072 + h * 128;
    const int pk  = (h < 8) ? 0 : 1;
    const int c0k = (h < 8) ? (2048 + h * 128) : ((h - 8) * 128);
    const u16* Kbase = Qh + ((int64_t)b * 2048 + pk) * 3072 + c0k;
    const u16* Vtz = Vt + ((int64_t)z << 17);
    float* attnZ = attn + ((int64_t)z << 20) + (int64_t)m0 * 1024;
    gld8_t64x128(Qbase, 6144, LQ, w, lane);          // Q 64x128 (2 ops)
    gld8_t64x128(Kbase,             6144, LKV[0], w, lane);
    gld8_t64x128(Kbase + 64 * 6144, 6144, LKV[1], w, lane);
    u32 pk0[32], pk1[32];
    float ssum0 = 0.f, ssum1 = 0.f;
#pragma unroll
    for (int t = 0; t < 16; ++t) {
        if (t == 15) { VWAIT(0); } else { VWAIT(2); }   // K(t) landed; K(t+1) in flight
        BARRIER;
        if (t < 14)
            gld8_t64x128(Kbase + (int64_t)(t + 2) * 64 * 6144, 6144, LKV[(t + 2) % 3], w, lane);
        f32x4 s0 = {}, s1 = {};
#pragma unroll
        for (int ks = 0; ks < 4; ++ks) {
            bf16x8 kf = *reinterpret_cast<const bf16x8*>(&LKV[t % 3][idxT(kt * 16 + rl, ks * 4 + gk)]);
            bf16x8 q0 = *reinterpret_cast<const bf16x8*>(&LQ[idxT(qh * 32 + rl, ks * 4 + gk)]);
            bf16x8 q1 = *reinterpret_cast<const bf16x8*>(&LQ[idxT(qh * 32 + 16 + rl, ks * 4 + gk)]);
            s0 = __builtin_amdgcn_mfma_f32_16x16x32_bf16(kf, q0, s0, 0, 0, 0);
            s1 = __builtin_amdgcn_mfma_f32_16x16x32_bf16(kf, q1, s1, 0, 0, 0);
        }
        float p0[4], p1[4];
#pragma unroll
        for (int j = 0; j < 4; ++j) {
            p0[j] = __expf(s0[j] * 0.125f); ssum0 += p0[j];
            p1[j] = __expf(s1[j] * 0.125f); ssum1 += p1[j];
        }
        pk0[2 * t]     = cvtpk(p0[0], p0[1]);
        pk1[2 * t]     = cvtpk(p0[2], p0[3]);
        pk0[2 * t + 1] = cvtpk(p1[0], p1[1]);
        pk1[2 * t + 1] = cvtpk(p1[2], p1[3]);
    }
    ssum0 += __shfl_xor(ssum0, 16); ssum0 += __shfl_xor(ssum0, 32);
    ssum1 += __shfl_xor(ssum1, 16); ssum1 += __shfl_xor(ssum1, 32);
    if (lane < 16) { pS[w][lane] = ssum0; pS[w][16 + lane] = ssum1; }
    LWAIT; BARRIER;                                  // all K readers done; buf0/1 free
    gld8_v128x64(Vtz,      1024, LKV[0], w, lane);   // V chunks 0,1 overlap stats
    gld8_v128x64(Vtz + 64, 1024, LKV[1], w, lane);
    if (tid < 64) {
        const int qb = (tid >> 5) << 2;              // q-half -> wave group base
        rowInv[tid] = 1.0f / (pS[qb][tid & 31] + pS[qb + 1][tid & 31]
                              + pS[qb + 2][tid & 31] + pS[qb + 3][tid & 31]);
    }
    LWAIT; BARRIER;
    const float Iq0 = rowInv[qh * 32 + rl], Iq1 = rowInv[qh * 32 + 16 + rl];
    float IqO[4];
#pragma unroll
    for (int j = 0; j < 4; ++j) IqO[j] = rowInv[qq * 16 + r4 + j];
    f32x4 po[4] = {};
#pragma unroll
    for (int t = 0; t < 16; ++t) {
        if (t == 0)       { VWAIT(2); }
        else if (t == 1)  { VWAIT(4); }
        else if (t == 15) { VWAIT(4); }
        else              { VWAIT(6); }
        BARRIER;
        if (t < 14)
            gld8_v128x64(Vtz + (t + 2) * 64, 1024, LKV[(t + 2) % 3], w, lane);
        const u32 a0 = pk0[2 * t], a1 = pk1[2 * t];
        const u32 b0 = pk0[2 * t + 1], b1 = pk1[2 * t + 1];
        *reinterpret_cast<uint2*>(&Ph[(qh * 32 + rl) * 72 + kt * 16 + r4])
            = make_uint2(a0, a1);
        *reinterpret_cast<uint2*>(&Ph[(qh * 32 + 16 + rl) * 72 + kt * 16 + r4])
            = make_uint2(b0, b1);
        *reinterpret_cast<float4*>(&attnZ[(int64_t)(qh * 32 + rl) * 1024 + t * 64 + kt * 16 + r4])
            = make_float4(__uint_as_float(a0 << 16) * Iq0,
                          __uint_as_float(a0 & 0xFFFF0000u) * Iq0,
                          __uint_as_float(a1 << 16) * Iq0,
                          __uint_as_float(a1 & 0xFFFF0000u) * Iq0);
        *reinterpret_cast<float4*>(&attnZ[(int64_t)(qh * 32 + 16 + rl) * 1024 + t * 64 + kt * 16 + r4])
            = make_float4(__uint_as_float(b0 << 16) * Iq1,
                          __uint_as_float(b0 & 0xFFFF0000u) * Iq1,
                          __uint_as_float(b1 << 16) * Iq1,
                          __uint_as_float(b1 & 0xFFFF0000u) * Iq1);
        LWAIT; BARRIER;                              // Ph visible (stores NOT drained)
        bf16x8 pa0 = *reinterpret_cast<const bf16x8*>(&Ph[(qq * 16 + rl) * 72 + gk * 8]);
        bf16x8 pa1 = *reinterpret_cast<const bf16x8*>(&Ph[(qq * 16 + rl) * 72 + 32 + gk * 8]);
#pragma unroll
        for (int n = 0; n < 4; ++n) {
            bf16x8 bv0 = *reinterpret_cast<const bf16x8*>(&LKV[t % 3][idxV(sv * 64 + n * 16 + rl, gk)]);
            bf16x8 bv1 = *reinterpret_cast<const bf16x8*>(&LKV[t % 3][idxV(sv * 64 + n * 16 + rl, 4 + gk)]);
            po[n] = __builtin_amdgcn_mfma_f32_16x16x32_bf16(pa0, bv0, po[n], 0, 0, 0);
            po[n] = __builtin_amdgcn_mfma_f32_16x16x32_bf16(pa1, bv1, po[n], 0, 0, 0);
        }
    }
    const int poh = h >> 3, cb2 = (h & 7) << 7;
#pragma unroll
    for (int n = 0; n < 4; ++n)
#pragma unroll
        for (int j = 0; j < 4; ++j) {
            const int qrow = m0 + qq * 16 + r4 + j;
            Obf[((int64_t)b * 2048 + 2 * qrow + poh) * 1024
                + cb2 + sv * 64 + n * 16 + rl] = f2bf(po[n][j] * IqO[j]);
        }
}

extern "C" void kernel_launch(void* const* d_in, const int* in_sizes, int n_in,
                              void* d_out, int out_size, void* d_ws, size_t ws_size,
                              hipStream_t stream) {
    const float* x     = (const float*)d_in[0];
    const float* ctx   = (const float*)d_in[1];
    const float* wqkv  = (const float*)d_in[2];
    const float* wproj = (const float*)d_in[3];
    const float* bias  = (const float*)d_in[4];
    float* out  = (float*)d_out;                 // [4,2048,1024]
    float* attn = out + 8388608;                 // [4,16,1024,1024] f32

    // ws (u16), total 92.3 MB
    u16* Qh  = (u16*)d_ws;                       // [8192,3072]
    u16* Vt  = Qh + 25165824;                    // [64,128,1024]
    u16* Wh  = Vt + 8388608;                     // [3072,1024]
    u16* Phw = Wh + 3145728;                     // [1024,1024]
    u16* Obf = Phw + 1048576;                    // [8192,1024]

    // X bf16 plane parked in the attn region (dead once k1 finishes)
    u16* Xh = (u16*)attn;                        // [8192,1024]

    k0_all            <<<dim3(6144), 256, 0, stream>>>(wqkv, x, ctx, wproj, Wh, Xh, Phw);
    gemm8p<false, 24> <<<dim3(768),  512, 0, stream>>>(Xh, Wh, nullptr, Qh, nullptr);
    k0v_vt            <<<dim3(8, 64), 256, 0, stream>>>(Qh, Vt);
    k23_fused         <<<dim3(1024), 512, 0, stream>>>(Qh, Vt, attn, Obf);
    gemm8p<true, 8>   <<<dim3(256),  512, 0, stream>>>(Obf, Phw, bias, nullptr, out);
}